// Round 9
// baseline (56707.343 us; speedup 1.0000x reference)
//
#include <hip/hip_runtime.h>
#include <hip/hip_cooperative_groups.h>
#include <cmath>

namespace cg = cooperative_groups;

#define Hdim 768
#define Bb 32
#define Kb 5
#define Ss 64
#define Vv 30522
#define Tt 40
#define SEPTOK 102
#define KCF 16
#define PADWF 259

typedef __attribute__((ext_vector_type(2))) float f32x2;
typedef __attribute__((ext_vector_type(4))) float f32x4;

struct Params {
    const float *src, *E, *Wa, *Ua, *va, *W_ih, *W_hh, *b_ih, *b_hh, *Wo, *bo;
    float *srcWa, *hA, *hB, *h_tmp, *h_gF, *hUa, *xbufF, *ctx, *gx, *gh, *logits;
    float *mx, *lgs, *scores, *ended, *lengths;
    int *toks_cur, *maps_cur, *toks_all, *maps_all, *outTok;
};

// ------------------------- shared top-k helpers ----------------------------
__device__ __forceinline__ bool betterf(float va, int ja, float vb, int jb) {
    return (va > vb) || (va == vb && ja < jb);
}
__device__ __forceinline__ void ins5(float* tv, int* tj, float v, int j) {
    if (!betterf(v, j, tv[4], tj[4])) return;
    tv[4] = v; tj[4] = j;
#pragma unroll
    for (int q = 4; q > 0; q--) {
        if (betterf(tv[q], tj[q], tv[q - 1], tj[q - 1])) {
            float t = tv[q]; tv[q] = tv[q - 1]; tv[q - 1] = t;
            int  ti = tj[q]; tj[q] = tj[q - 1]; tj[q - 1] = ti;
        }
    }
}

// ======================= FUSED COOPERATIVE PATH ============================
union SMemF {                                       // max member ~17.9 KB
    struct { float xs[16][20]; float wtp[KCF][PADWF]; } g;
    struct { float hu[Hdim]; float va_s[Hdim]; float e_s[Ss]; float a_s[Ss]; } at;
    struct { float redf[256]; double redd[256]; } ls;
    struct {
        float sc[Kb], den[Kb], end[Kb], len[Kb], mxs[Kb], lgv[Kb];
        float mv[256 * 5]; int mj[256 * 5];
        float rv[256]; int rj[256]; int selj[Kb];
    } tk;
};

// 16x256 GEMM tile, K-chunk 16, two-level accumulation (round-7-proven noise).
// xsrc: 0=gathered h_old (zeros at t==0), 1=[emb|ctx], 2=h_new(rowMul), 3=src
__device__ void gemm_tile16(SMemF& sm, const Params& P, int t, int xsrc,
    int n0, int i0, int Pdim, const float* __restrict__ W, int ldW, bool imaj,
    const float* __restrict__ bias, float* __restrict__ outp, int ldO, int Icap)
{
    int tid = threadIdx.x;
    const float* h_old = (t & 1) ? P.hB : P.hA;
    const float* h_new = (t & 1) ? P.hA : P.hB;
    int rowMul = (t == 0) ? Kb : 1;
    float acc[16];
#pragma unroll
    for (int r = 0; r < 16; r++) acc[r] = 0.f;

    for (int c0 = 0; c0 < Pdim; c0 += KCF) {
        __syncthreads();
        // ---- stage X: 16 rows x 16 p, 1 float/thread
        {
            int r = tid >> 4, p = tid & 15;
            int n = n0 + r;
            float v = 0.f;
            if (xsrc == 0) {
                if (t != 0) {
                    int bk = (n / Kb) * Kb + P.maps_cur[n];
                    v = h_old[(size_t)bk * Hdim + c0 + p];
                }
            } else if (xsrc == 1) {
                int pg = c0 + p;
                if (pg < Hdim) {
                    int tok = (t == 0) ? SEPTOK : P.toks_cur[n];
                    v = P.E[(size_t)tok * Hdim + pg];
                } else {
                    v = P.ctx[(size_t)n * Hdim + (pg - Hdim)];
                }
            } else if (xsrc == 2) {
                v = h_new[((size_t)n * rowMul) * Hdim + c0 + p];
            } else {
                v = P.src[(size_t)n * Hdim + c0 + p];
            }
            sm.g.xs[r][p] = v;
        }
        // ---- stage W tile -> wtp[p][c]
        if (imaj) {
            int gi = i0 + tid; if (gi >= Icap) gi = Icap - 1;
            const float* wp = W + (size_t)gi * ldW + c0;
#pragma unroll
            for (int p4 = 0; p4 < 4; p4++) {
                f32x4 a = *(const f32x4*)(wp + p4 * 4);
#pragma unroll
                for (int u = 0; u < 4; u++) sm.g.wtp[p4 * 4 + u][tid] = a[u];
            }
        } else {
            int p = tid & 15, cl = (tid >> 4) * 16;
            const float* wp = W + (size_t)(c0 + p) * ldW + i0 + cl;
#pragma unroll
            for (int e = 0; e < 4; e++) {
                f32x4 a = *(const f32x4*)(wp + e * 4);
#pragma unroll
                for (int u = 0; u < 4; u++) sm.g.wtp[p][cl + e * 4 + u] = a[u];
            }
        }
        __syncthreads();
        // ---- compute chunk partial, then add to running acc (two-level)
        float part[16];
#pragma unroll
        for (int r = 0; r < 16; r++) part[r] = 0.f;
#pragma unroll
        for (int p4 = 0; p4 < KCF / 4; p4++) {
            float w0 = sm.g.wtp[p4 * 4 + 0][tid];
            float w1 = sm.g.wtp[p4 * 4 + 1][tid];
            float w2 = sm.g.wtp[p4 * 4 + 2][tid];
            float w3 = sm.g.wtp[p4 * 4 + 3][tid];
#pragma unroll
            for (int r = 0; r < 16; r++) {
                f32x4 xv = *(const f32x4*)&sm.g.xs[r][p4 * 4];
                float s = part[r];
                s = fmaf(xv.x, w0, s);
                s = fmaf(xv.y, w1, s);
                s = fmaf(xv.z, w2, s);
                s = fmaf(xv.w, w3, s);
                part[r] = s;
            }
        }
#pragma unroll
        for (int r = 0; r < 16; r++) acc[r] = __fadd_rn(acc[r], part[r]);
    }
    int ic = i0 + tid;
    if (ic < Icap) {
        float bv = bias ? bias[ic] : 0.f;
#pragma unroll
        for (int r = 0; r < 16; r++) {
            float v = acc[r];
            if (bias) v = __fadd_rn(v, bv);
            outp[(size_t)(n0 + r) * ldO + ic] = v;
        }
    }
}

// srcWa = src @ Wa (one-time, normal launch; used by BOTH paths)
__global__ __launch_bounds__(256) void srcwa_k(Params P)
{
    __shared__ SMemF sm;
    int rt = blockIdx.x / 3, ct = blockIdx.x % 3;
    gemm_tile16(sm, P, 1, 3, rt * 16, ct * 256, Hdim, P.Wa, Hdim, false, nullptr,
                P.srcWa, Hdim, Hdim);
}

__global__ __launch_bounds__(256) void fused_k(Params P)
{
    cg::grid_group grid = cg::this_grid();
    __shared__ SMemF sm;
    const int blk = blockIdx.x, tid = threadIdx.x;
    const int gdim = gridDim.x;

    for (int t = 0; t < Tt; t++) {
        int N = (t == 0) ? Bb : Bb * Kb;
        int Kcur = (t == 0) ? 1 : Kb;
        int nrt = N / 16;
        float* h_new = (t & 1) ? P.hA : P.hB;
        const float* h_old = (t & 1) ? P.hB : P.hA;

        // ---- PHASE B: hUa = h @ Ua  AND  gh = h @ W_hh^T + b_hh ----
        {
            int nUa = nrt * 3, nHH = nrt * 9;
            for (int task = blk; task < nUa + nHH; task += gdim) {
                if (task < nUa) {
                    int rt = task / 3, ct = task % 3;
                    gemm_tile16(sm, P, t, 0, rt * 16, ct * 256, Hdim,
                                P.Ua, Hdim, false, nullptr, P.hUa, Hdim, Hdim);
                } else {
                    int k = task - nUa; int rt = k / 9, ct = k % 9;
                    gemm_tile16(sm, P, t, 0, rt * 16, ct * 256, Hdim,
                                P.W_hh, Hdim, true, P.b_hh, P.gh, 2304, 2304);
                }
            }
        }
        grid.sync();

        // ---- PHASE C: attention -> ctx (round-7 exact math) ----
        for (int n = blk; n < N; n += gdim) {
            int b = n / Kcur;
            for (int j = tid; j < Hdim; j += 256) {
                sm.at.hu[j]   = P.hUa[(size_t)n * Hdim + j];
                sm.at.va_s[j] = P.va[j];
            }
            __syncthreads();
            int wv = tid >> 6, ln = tid & 63;
            for (int s = wv * 16; s < wv * 16 + 16; s++) {
                const float* sw = P.srcWa + (size_t)(b * Ss + s) * Hdim;
                double p = 0.0;
                for (int j = ln; j < Hdim; j += 64) {
                    float tv = (float)tanh((double)__fadd_rn(sw[j], sm.at.hu[j]));
                    p = ::fma((double)tv, (double)sm.at.va_s[j], p);
                }
                for (int off = 32; off; off >>= 1) p += __shfl_down(p, off, 64);
                if (ln == 0) sm.at.e_s[s] = (float)p;
            }
            __syncthreads();
            if (tid < 64) {
                float v = sm.at.e_s[tid], m = v;
                for (int off = 32; off; off >>= 1) m = fmaxf(m, __shfl_xor(m, off, 64));
                float p = (float)exp((double)__fsub_rn(v, m));
                double sum = (double)p;
                for (int off = 32; off; off >>= 1) sum += __shfl_xor(sum, off, 64);
                sm.at.a_s[tid] = __fdiv_rn(p, (float)sum);
            }
            __syncthreads();
            for (int j = tid; j < Hdim; j += 256) {
                double acc = 0.0;
                for (int s = 0; s < Ss; s++)
                    acc = ::fma((double)sm.at.a_s[s],
                                (double)P.src[(size_t)(b * Ss + s) * Hdim + j], acc);
                P.ctx[(size_t)n * Hdim + j] = (float)acc;
            }
            __syncthreads();
        }
        grid.sync();

        // ---- PHASE D: gx = [emb|ctx] @ W_ih^T + b_ih ----
        for (int task = blk; task < nrt * 9; task += gdim) {
            int rt = task / 9, ct = task % 9;
            gemm_tile16(sm, P, t, 1, rt * 16, ct * 256, 1536,
                        P.W_ih, 1536, true, P.b_ih, P.gx, 2304, 2304);
        }
        grid.sync();

        // ---- PHASE E: GRU gate -> h_new (t0: broadcast into 5 slots) ----
        for (int idx = blk * 256 + tid; idx < N * Hdim; idx += gdim * 256) {
            int n = idx / Hdim, i = idx - n * Hdim;
            const float* gxr = P.gx + (size_t)n * 2304;
            const float* ghr = P.gh + (size_t)n * 2304;
            float xr = gxr[i], xz = gxr[768 + i], xn = gxr[1536 + i];
            float hr = ghr[i], hz = ghr[768 + i], hn = ghr[1536 + i];
            float r  = (float)(1.0 / (1.0 + exp(-(double)__fadd_rn(xr, hr))));
            float z  = (float)(1.0 / (1.0 + exp(-(double)__fadd_rn(xz, hz))));
            float nn = (float)tanh((double)__fadd_rn(xn, __fmul_rn(r, hn)));
            float hv = (t == 0) ? 0.f
                     : h_old[((size_t)((n / Kb) * Kb + P.maps_cur[n])) * Hdim + i];
            float h2 = __fadd_rn(__fmul_rn(__fsub_rn(1.f, z), nn), __fmul_rn(z, hv));
            if (t == 0) {
                for (int k = 0; k < Kb; k++)
                    h_new[(size_t)(n * Kb + k) * Hdim + i] = h2;
            } else {
                h_new[(size_t)n * Hdim + i] = h2;
            }
        }
        grid.sync();

        // ---- PHASE F: logits = h2 @ Wo^T + bo ----
        for (int task = blk; task < nrt * 120; task += gdim) {
            int rt = task / 120, ct = task % 120;
            gemm_tile16(sm, P, t, 2, rt * 16, ct * 256, Hdim,
                        P.Wo, Hdim, true, P.bo, P.logits, Vv, Vv);
        }
        grid.sync();

        // ---- PHASE G: lse per row ----
        for (int n = blk; n < N; n += gdim) {
            const float* lg = P.logits + (size_t)n * Vv;
            float m = -INFINITY;
            for (int v = tid; v < Vv; v += 256) m = fmaxf(m, lg[v]);
            sm.ls.redf[tid] = m; __syncthreads();
            for (int off = 128; off; off >>= 1) {
                if (tid < off) sm.ls.redf[tid] = fmaxf(sm.ls.redf[tid], sm.ls.redf[tid + off]);
                __syncthreads();
            }
            m = sm.ls.redf[0];
            double s = 0.0;
            for (int v = tid; v < Vv; v += 256) {
                float ex = (float)exp((double)__fsub_rn(lg[v], m));
                s += (double)ex;
            }
            __syncthreads();
            sm.ls.redd[tid] = s; __syncthreads();
            for (int off = 128; off; off >>= 1) {
                if (tid < off) sm.ls.redd[tid] += sm.ls.redd[tid + off];
                __syncthreads();
            }
            if (tid == 0) {
                P.mx[n] = m;
                float sf = (float)sm.ls.redd[0];
                P.lgs[n] = (float)log((double)sf);
            }
            __syncthreads();
        }
        grid.sync();

        // ---- PHASE H: top-5 per batch ----
        for (int b = blk; b < Bb; b += gdim) {
            if (tid < Kb) {
                if (t == 0) {
                    sm.tk.sc[tid] = 0.f; sm.tk.end[tid] = 0.f; sm.tk.len[tid] = 0.f;
                    sm.tk.den[tid] = 1.f;
                    sm.tk.mxs[tid] = P.mx[b]; sm.tk.lgv[tid] = P.lgs[b];
                } else {
                    float e0 = P.ended[b * Kb + tid];
                    float ln = __fadd_rn(P.lengths[b * Kb + tid], (e0 == 0.f) ? 1.f : 0.f);
                    sm.tk.sc[tid]  = P.scores[b * Kb + tid];
                    sm.tk.end[tid] = e0;
                    sm.tk.len[tid] = ln;
                    sm.tk.den[tid] = (tid < Kb - 1) ? (float)pow((double)ln, (double)0.7f) : 1.f;
                    sm.tk.mxs[tid] = P.mx[b * Kb + tid];
                    sm.tk.lgv[tid] = P.lgs[b * Kb + tid];
                }
            }
            __syncthreads();
            const float* lbase = P.logits + (size_t)b * Kcur * Vv;
            float tv[5]; int tj[5];
#pragma unroll
            for (int q = 0; q < 5; q++) { tv[q] = -INFINITY; tj[q] = 0x7fffffff; }
            for (int k = 0; k < Kcur; k++) {
                if (sm.tk.end[k] == 0.f) {
                    float m = sm.tk.mxs[k], l = sm.tk.lgv[k];
                    float sck = sm.tk.sc[k], den = sm.tk.den[k];
                    const float* lg = lbase + (size_t)k * Vv;
                    for (int v = tid; v < Vv; v += 256) {
                        float lp  = __fsub_rn(__fsub_rn(lg[v], m), l);
                        float val = __fdiv_rn(__fadd_rn(lp, sck), den);
                        ins5(tv, tj, val, k * Vv + v);
                    }
                } else if (tid == 0) {
                    float val = __fdiv_rn(sm.tk.sc[k], sm.tk.den[k]);
                    ins5(tv, tj, val, k * Vv + SEPTOK);
                }
            }
#pragma unroll
            for (int q = 0; q < 5; q++) { sm.tk.mv[tid * 5 + q] = tv[q]; sm.tk.mj[tid * 5 + q] = tj[q]; }
            __syncthreads();
            for (int pass = 0; pass < Kb; pass++) {
                float bv = -INFINITY; int bj = 0x7fffffff;
#pragma unroll
                for (int q = 0; q < 5; q++) {
                    float v = sm.tk.mv[tid * 5 + q]; int j = sm.tk.mj[tid * 5 + q];
                    if (betterf(v, j, bv, bj)) { bv = v; bj = j; }
                }
                sm.tk.rv[tid] = bv; sm.tk.rj[tid] = bj;
                __syncthreads();
                for (int off = 128; off; off >>= 1) {
                    if (tid < off) {
                        float ov = sm.tk.rv[tid + off]; int oj = sm.tk.rj[tid + off];
                        if (betterf(ov, oj, sm.tk.rv[tid], sm.tk.rj[tid])) {
                            sm.tk.rv[tid] = ov; sm.tk.rj[tid] = oj;
                        }
                    }
                    __syncthreads();
                }
                if (tid == 0) sm.tk.selj[pass] = sm.tk.rj[0];
                __syncthreads();
#pragma unroll
                for (int q = 0; q < 5; q++)
                    if (sm.tk.mj[tid * 5 + q] == sm.tk.selj[pass]) {
                        sm.tk.mv[tid * 5 + q] = -INFINITY; sm.tk.mj[tid * 5 + q] = 0x7fffffff;
                    }
                __syncthreads();
            }
            if (tid == 0) {
                for (int q = 0; q < Kb; q++) {
                    int jj = sm.tk.selj[q];
                    int pk = jj / Vv, vv = jj - pk * Vv;
                    float lp;
                    if (sm.tk.end[pk] == 0.f)
                        lp = __fsub_rn(__fsub_rn(lbase[(size_t)pk * Vv + vv], sm.tk.mxs[pk]),
                                       sm.tk.lgv[pk]);
                    else
                        lp = (vv == SEPTOK) ? 0.f : -1e9f;
                    float cand = __fadd_rn(lp, sm.tk.sc[pk]);
                    P.scores[b * Kb + q]   = cand;
                    P.toks_cur[b * Kb + q] = vv;
                    P.maps_cur[b * Kb + q] = (t == 0) ? 0 : pk;
                    if (t == 0) {
                        P.ended[b * Kb + q]   = 0.f;
                        P.lengths[b * Kb + q] = 0.f;
                    } else {
                        P.ended[b * Kb + q]   = (vv == SEPTOK) ? 1.f : sm.tk.end[q];
                        P.lengths[b * Kb + q] = sm.tk.len[q];
                    }
                    P.toks_all[(size_t)t * Bb * Kb + b * Kb + q] = vv;
                    P.maps_all[(size_t)t * Bb * Kb + b * Kb + q] = (t == 0) ? 0 : pk;
                }
            }
            __syncthreads();
        }
        grid.sync();
    }

    if (blk == 0 && tid < Bb) {
        int b = tid;
        int best = 0; float bvv = P.scores[b * Kb];
        for (int k = 1; k < Kb; k++) {
            float v = P.scores[b * Kb + k];
            if (v > bvv) { bvv = v; best = k; }
        }
        int cur = best;
        for (int t = Tt - 1; t >= 0; t--) {
            P.outTok[b * Tt + t] = P.toks_all[t * Bb * Kb + b * Kb + cur];
            cur = P.maps_all[t * Bb * Kb + b * Kb + cur];
        }
    }
}

// ===================== FALLBACK PATH (round-7, proven) =====================
template<int CPT, bool PMAJOR>
__global__ __launch_bounds__(256) void gemmF_k(int P, int I, int xrs, int ld,
    const float* __restrict__ Xf, const float* __restrict__ W,
    const float* __restrict__ bias, float* __restrict__ out)
{
    __shared__ float xs[16][18];
    __shared__ float wt[CPT * 256][18];
    int tid = threadIdx.x;
    int n0 = blockIdx.y * 16;
    int i0 = blockIdx.x * (CPT * 256);
    float acc[CPT][16];
#pragma unroll
    for (int s = 0; s < CPT; s++)
#pragma unroll
        for (int r = 0; r < 16; r++) acc[s][r] = 0.f;

    int nch = P / 16;
    for (int c = 0; c < nch; c++) {
        int p0 = c * 16;
        __syncthreads();
        {
            int r = tid >> 4, p = tid & 15;
            xs[r][p] = Xf[(size_t)(n0 + r) * xrs + p0 + p];
        }
        if (PMAJOR) {
            const int LPR = CPT * 64;
            const int RPI = 256 / LPR;
            int i4 = (tid % LPR) * 4;
            int pl = tid / LPR;
#pragma unroll
            for (int it = 0; it < 16 / RPI; ++it) {
                int p = pl + it * RPI;
                int gi = i0 + i4;
                f32x4 v = {0.f, 0.f, 0.f, 0.f};
                if (gi + 3 < I) {
                    v = *(const f32x4*)&W[(size_t)(p0 + p) * ld + gi];
                } else {
#pragma unroll
                    for (int q = 0; q < 4; q++)
                        if (gi + q < I) v[q] = W[(size_t)(p0 + p) * ld + gi + q];
                }
                wt[i4 + 0][p] = v[0]; wt[i4 + 1][p] = v[1];
                wt[i4 + 2][p] = v[2]; wt[i4 + 3][p] = v[3];
            }
        } else {
            int p4 = (tid & 3) * 4;
            int il = tid >> 2;
#pragma unroll
            for (int it = 0; it < CPT * 4; ++it) {
                int i_loc = il + it * 64;
                long long gi = i0 + i_loc;
                if (gi >= I) gi = I - 1;
                f32x4 v = *(const f32x4*)&W[(size_t)gi * ld + p0 + p4];
                wt[i_loc][p4 + 0] = v[0]; wt[i_loc][p4 + 1] = v[1];
                wt[i_loc][p4 + 2] = v[2]; wt[i_loc][p4 + 3] = v[3];
            }
        }
        __syncthreads();
        float part[CPT][16];
#pragma unroll
        for (int s = 0; s < CPT; s++)
#pragma unroll
            for (int r = 0; r < 16; r++) part[s][r] = 0.f;
#pragma unroll
        for (int p2 = 0; p2 < 16; p2 += 2) {
            f32x2 wv[CPT];
#pragma unroll
            for (int s = 0; s < CPT; s++)
                wv[s] = *(const f32x2*)&wt[s * 256 + tid][p2];
#pragma unroll
            for (int r = 0; r < 16; r++) {
                f32x2 xv = *(const f32x2*)&xs[r][p2];
#pragma unroll
                for (int s = 0; s < CPT; s++) {
                    part[s][r] = fmaf(xv.x, wv[s].x, part[s][r]);
                    part[s][r] = fmaf(xv.y, wv[s].y, part[s][r]);
                }
            }
        }
#pragma unroll
        for (int s = 0; s < CPT; s++)
#pragma unroll
            for (int r = 0; r < 16; r++) acc[s][r] = __fadd_rn(acc[s][r], part[s][r]);
    }
#pragma unroll
    for (int s = 0; s < CPT; s++) {
        int cs = i0 + s * 256 + tid;
        if (cs < I) {
            float bv = bias ? bias[cs] : 0.f;
#pragma unroll
            for (int r = 0; r < 16; r++) {
                float v = acc[s][r];
                if (bias) v = __fadd_rn(v, bv);
                out[(size_t)(n0 + r) * I + cs] = v;
            }
        }
    }
}

__global__ __launch_bounds__(256) void gather_k(int N, int Kcur,
    const int* __restrict__ maps, const int* __restrict__ toks,
    const float* __restrict__ h_beam, const float* __restrict__ E,
    float* __restrict__ h_g, float* __restrict__ xbuf)
{
    int n = blockIdx.x;
    if (n >= N) return;
    int b = n / Kcur;
    int tok = toks ? toks[n] : SEPTOK;
    const float* er = E + (size_t)tok * Hdim;
    if (maps) {
        const float* hs = h_beam + (size_t)(b * Kb + maps[n]) * Hdim;
        for (int j = threadIdx.x; j < Hdim; j += 256) {
            h_g[(size_t)n * Hdim + j]  = hs[j];
            xbuf[(size_t)n * 1536 + j] = er[j];
        }
    } else {
        for (int j = threadIdx.x; j < Hdim; j += 256) {
            h_g[(size_t)n * Hdim + j]  = 0.f;
            xbuf[(size_t)n * 1536 + j] = er[j];
        }
    }
}

__global__ __launch_bounds__(256) void bcast_k(const float* __restrict__ h_tmp,
                                               float* __restrict__ h_beam)
{
    int b = blockIdx.x;
    for (int j = threadIdx.x; j < Hdim; j += 256) {
        float v = h_tmp[(size_t)b * Hdim + j];
        for (int k = 0; k < Kb; k++)
            h_beam[(size_t)(b * Kb + k) * Hdim + j] = v;
    }
}

__global__ __launch_bounds__(256) void attn2_k(int N, int Kcur,
    const float* __restrict__ hUa, const float* __restrict__ srcWa,
    const float* __restrict__ src, const float* __restrict__ va,
    float* __restrict__ xbuf)
{
    __shared__ float hu[Hdim];
    __shared__ float va_s[Hdim];
    __shared__ float e_s[Ss];
    __shared__ float a_s[Ss];
    int n = blockIdx.x, tid = threadIdx.x;
    if (n >= N) return;
    int b = n / Kcur;
    for (int j = tid; j < Hdim; j += 256) {
        hu[j]   = hUa[(size_t)n * Hdim + j];
        va_s[j] = va[j];
    }
    __syncthreads();
    int wv = tid >> 6, ln = tid & 63;
    for (int s = wv * 16; s < wv * 16 + 16; s++) {
        const float* sw = srcWa + (size_t)(b * Ss + s) * Hdim;
        double p = 0.0;
        for (int j = ln; j < Hdim; j += 64) {
            float tv = (float)tanh((double)__fadd_rn(sw[j], hu[j]));
            p = ::fma((double)tv, (double)va_s[j], p);
        }
        for (int off = 32; off; off >>= 1) p += __shfl_down(p, off, 64);
        if (ln == 0) e_s[s] = (float)p;
    }
    __syncthreads();
    if (tid < 64) {
        float v = e_s[tid], m = v;
        for (int off = 32; off; off >>= 1) m = fmaxf(m, __shfl_xor(m, off, 64));
        float p = (float)exp((double)__fsub_rn(v, m));
        double sum = (double)p;
        for (int off = 32; off; off >>= 1) sum += __shfl_xor(sum, off, 64);
        a_s[tid] = __fdiv_rn(p, (float)sum);
    }
    __syncthreads();
    for (int j = tid; j < Hdim; j += 256) {
        double acc = 0.0;
        for (int s = 0; s < Ss; s++)
            acc = ::fma((double)a_s[s], (double)src[(size_t)(b * Ss + s) * Hdim + j], acc);
        xbuf[(size_t)n * 1536 + 768 + j] = (float)acc;
    }
}

__global__ __launch_bounds__(256) void gate_k(int N,
    const float* __restrict__ gx, const float* __restrict__ gh,
    const float* __restrict__ h_g, float* __restrict__ h_out)
{
    int idx = blockIdx.x * 256 + threadIdx.x;
    if (idx >= N * Hdim) return;
    int n = idx / Hdim, i = idx - n * Hdim;
    const float* gxr = gx + (size_t)n * 2304;
    const float* ghr = gh + (size_t)n * 2304;
    float xr = gxr[i], xz = gxr[768 + i], xn = gxr[1536 + i];
    float hr = ghr[i], hz = ghr[768 + i], hn = ghr[1536 + i];
    float r  = (float)(1.0 / (1.0 + exp(-(double)__fadd_rn(xr, hr))));
    float z  = (float)(1.0 / (1.0 + exp(-(double)__fadd_rn(xz, hz))));
    float nn = (float)tanh((double)__fadd_rn(xn, __fmul_rn(r, hn)));
    float hv = h_g[(size_t)n * Hdim + i];
    float h2 = __fadd_rn(__fmul_rn(__fsub_rn(1.f, z), nn), __fmul_rn(z, hv));
    h_out[(size_t)n * Hdim + i] = h2;
}

__global__ __launch_bounds__(256) void lse_k(int N,
    const float* __restrict__ logits, float* __restrict__ mx, float* __restrict__ lgs)
{
    __shared__ float  redf[256];
    __shared__ double redd[256];
    int n = blockIdx.x, tid = threadIdx.x;
    const float* lg = logits + (size_t)n * Vv;
    float m = -INFINITY;
    for (int v = tid; v < Vv; v += 256) m = fmaxf(m, lg[v]);
    redf[tid] = m; __syncthreads();
    for (int off = 128; off; off >>= 1) {
        if (tid < off) redf[tid] = fmaxf(redf[tid], redf[tid + off]);
        __syncthreads();
    }
    m = redf[0];
    double s = 0.0;
    for (int v = tid; v < Vv; v += 256) {
        float ex = (float)exp((double)__fsub_rn(lg[v], m));
        s += (double)ex;
    }
    redd[tid] = s; __syncthreads();
    for (int off = 128; off; off >>= 1) {
        if (tid < off) redd[tid] += redd[tid + off];
        __syncthreads();
    }
    if (tid == 0) {
        mx[n] = m;
        float sf = (float)redd[0];
        lgs[n] = (float)log((double)sf);
    }
}

__global__ __launch_bounds__(256) void topk5_k(int t,
    const float* __restrict__ logits, const float* __restrict__ mx, const float* __restrict__ lgs,
    float* scores, float* ended, float* lengths,
    int* toks_cur, int* maps_cur, int* toks_all, int* maps_all)
{
    __shared__ float sc_s[Kb], den_s[Kb], end_s[Kb], len_s[Kb], mx_s[Kb], lg_s[Kb];
    __shared__ float mv[256 * 5];
    __shared__ int   mj[256 * 5];
    __shared__ float rv[256];
    __shared__ int   rj[256];
    __shared__ int   selj[Kb];
    int b = blockIdx.x, tid = threadIdx.x;
    int Kcur = (t == 0) ? 1 : Kb;
    if (tid < Kb) {
        if (t == 0) {
            sc_s[tid] = 0.f; end_s[tid] = 0.f; len_s[tid] = 0.f; den_s[tid] = 1.f;
            mx_s[tid] = mx[b]; lg_s[tid] = lgs[b];
        } else {
            float e0 = ended[b * Kb + tid];
            float ln = __fadd_rn(lengths[b * Kb + tid], (e0 == 0.f) ? 1.f : 0.f);
            sc_s[tid]  = scores[b * Kb + tid];
            end_s[tid] = e0;
            len_s[tid] = ln;
            den_s[tid] = (tid < Kb - 1) ? (float)pow((double)ln, (double)0.7f) : 1.f;
            mx_s[tid]  = mx[b * Kb + tid];
            lg_s[tid]  = lgs[b * Kb + tid];
        }
    }
    __syncthreads();
    const float* lbase = logits + (size_t)b * Kcur * Vv;
    float tv[5]; int tj[5];
#pragma unroll
    for (int q = 0; q < 5; q++) { tv[q] = -INFINITY; tj[q] = 0x7fffffff; }
    for (int k = 0; k < Kcur; k++) {
        if (end_s[k] == 0.f) {
            float m = mx_s[k], l = lg_s[k], sck = sc_s[k], den = den_s[k];
            const float* lg = lbase + (size_t)k * Vv;
            for (int v = tid; v < Vv; v += 256) {
                float lp  = __fsub_rn(__fsub_rn(lg[v], m), l);
                float val = __fdiv_rn(__fadd_rn(lp, sck), den);
                ins5(tv, tj, val, k * Vv + v);
            }
        } else if (tid == 0) {
            float val = __fdiv_rn(sc_s[k], den_s[k]);
            ins5(tv, tj, val, k * Vv + SEPTOK);
        }
    }
#pragma unroll
    for (int q = 0; q < 5; q++) { mv[tid * 5 + q] = tv[q]; mj[tid * 5 + q] = tj[q]; }
    __syncthreads();
    for (int pass = 0; pass < Kb; pass++) {
        float bv = -INFINITY; int bj = 0x7fffffff;
#pragma unroll
        for (int q = 0; q < 5; q++) {
            float v = mv[tid * 5 + q]; int j = mj[tid * 5 + q];
            if (betterf(v, j, bv, bj)) { bv = v; bj = j; }
        }
        rv[tid] = bv; rj[tid] = bj;
        __syncthreads();
        for (int off = 128; off; off >>= 1) {
            if (tid < off) {
                float ov = rv[tid + off]; int oj = rj[tid + off];
                if (betterf(ov, oj, rv[tid], rj[tid])) { rv[tid] = ov; rj[tid] = oj; }
            }
            __syncthreads();
        }
        if (tid == 0) selj[pass] = rj[0];
        __syncthreads();
#pragma unroll
        for (int q = 0; q < 5; q++)
            if (mj[tid * 5 + q] == selj[pass]) { mv[tid * 5 + q] = -INFINITY; mj[tid * 5 + q] = 0x7fffffff; }
        __syncthreads();
    }
    if (tid == 0) {
        for (int q = 0; q < Kb; q++) {
            int jj = selj[q];
            int pk = jj / Vv, vv = jj - pk * Vv;
            float lp;
            if (end_s[pk] == 0.f)
                lp = __fsub_rn(__fsub_rn(lbase[(size_t)pk * Vv + vv], mx_s[pk]), lg_s[pk]);
            else
                lp = (vv == SEPTOK) ? 0.f : -1e9f;
            float cand = __fadd_rn(lp, sc_s[pk]);
            scores[b * Kb + q]   = cand;
            toks_cur[b * Kb + q] = vv;
            maps_cur[b * Kb + q] = (t == 0) ? 0 : pk;
            if (t == 0) {
                ended[b * Kb + q]   = 0.f;
                lengths[b * Kb + q] = 0.f;
            } else {
                ended[b * Kb + q]   = (vv == SEPTOK) ? 1.f : end_s[q];
                lengths[b * Kb + q] = len_s[q];
            }
            toks_all[(size_t)t * Bb * Kb + b * Kb + q] = vv;
            maps_all[(size_t)t * Bb * Kb + b * Kb + q] = (t == 0) ? 0 : pk;
        }
    }
}

__global__ void back_k(const float* __restrict__ scores,
                       const int* __restrict__ toks_all, const int* __restrict__ maps_all,
                       int* __restrict__ out)
{
    int b = threadIdx.x;
    if (b >= Bb) return;
    int best = 0; float bvv = scores[b * Kb];
    for (int k = 1; k < Kb; k++) {
        float v = scores[b * Kb + k];
        if (v > bvv) { bvv = v; best = k; }
    }
    int cur = best;
    for (int t = Tt - 1; t >= 0; t--) {
        out[b * Tt + t] = toks_all[t * Bb * Kb + b * Kb + cur];
        cur = maps_all[t * Bb * Kb + b * Kb + cur];
    }
}

// ---------------------------------------------------------------------------
extern "C" void kernel_launch(void* const* d_in, const int* in_sizes, int n_in,
                              void* d_out, int out_size, void* d_ws, size_t ws_size,
                              hipStream_t stream)
{
    Params P;
    P.src  = (const float*)d_in[0];
    P.E    = (const float*)d_in[1];
    P.Wa   = (const float*)d_in[2];
    P.Ua   = (const float*)d_in[3];
    P.va   = (const float*)d_in[4];
    P.W_ih = (const float*)d_in[5];
    P.W_hh = (const float*)d_in[6];
    P.b_ih = (const float*)d_in[7];
    P.b_hh = (const float*)d_in[8];
    P.Wo   = (const float*)d_in[9];
    P.bo   = (const float*)d_in[10];
    P.outTok = (int*)d_out;

    char* w = (char*)d_ws;
    size_t used = 0;
    auto alloc = [&](size_t bytes) -> char* {
        char* p = w + used;
        used += (bytes + 255) & ~(size_t)255;
        return p;
    };
    P.srcWa   = (float*)alloc((size_t)Bb * Ss * Hdim * 4);
    P.hA      = (float*)alloc((size_t)Bb * Kb * Hdim * 4);
    P.hB      = (float*)alloc((size_t)Bb * Kb * Hdim * 4);
    P.h_tmp   = (float*)alloc((size_t)Bb * Hdim * 4);
    P.h_gF    = (float*)alloc((size_t)Bb * Kb * Hdim * 4);
    P.hUa     = (float*)alloc((size_t)Bb * Kb * Hdim * 4);
    P.xbufF   = (float*)alloc((size_t)Bb * Kb * 1536 * 4);
    P.ctx     = (float*)alloc((size_t)Bb * Kb * Hdim * 4);
    P.gx      = (float*)alloc((size_t)Bb * Kb * 2304 * 4);
    P.gh      = (float*)alloc((size_t)Bb * Kb * 2304 * 4);
    P.logits  = (float*)alloc((size_t)Bb * Kb * Vv * 4);
    P.mx      = (float*)alloc(Bb * Kb * 4);
    P.lgs     = (float*)alloc(Bb * Kb * 4);
    P.scores  = (float*)alloc(Bb * Kb * 4);
    P.ended   = (float*)alloc(Bb * Kb * 4);
    P.lengths = (float*)alloc(Bb * Kb * 4);
    P.toks_cur = (int*)alloc(Bb * Kb * 4);
    P.maps_cur = (int*)alloc(Bb * Kb * 4);
    P.toks_all = (int*)alloc((size_t)Tt * Bb * Kb * 4);
    P.maps_all = (int*)alloc((size_t)Tt * Bb * Kb * 4);

    // one-time srcWa (both paths consume it)
    srcwa_k<<<dim3(128 * 3), 256, 0, stream>>>(P);

    // --- size the cooperative grid from real occupancy (host query only) ---
    int dev = 0;
    (void)hipGetDevice(&dev);
    int nCU = 256;
    (void)hipDeviceGetAttribute(&nCU, hipDeviceAttributeMultiprocessorCount, dev);
    int maxAct = 0;
    if (hipOccupancyMaxActiveBlocksPerMultiprocessor(&maxAct, fused_k, 256, 0)
            != hipSuccess || maxAct < 1)
        maxAct = 1;
    long long gridLL = (long long)maxAct * (long long)nCU;
    if (gridLL > 2048) gridLL = 2048;
    if (gridLL < 1) gridLL = 1;
    dim3 grid((unsigned)gridLL);

    void* args[] = { (void*)&P };
    hipError_t err = hipLaunchCooperativeKernel((void*)fused_k, grid, dim3(256),
                                                args, 0, stream);
    if (err != hipSuccess) {
        (void)hipGetLastError();  // clear sticky error; run proven fallback
        for (int t = 0; t < Tt; t++) {
            int N  = (t == 0) ? Bb : Bb * Kb;
            int Kc = (t == 0) ? 1 : Kb;
            const int* mp = (t == 0) ? nullptr : P.maps_cur;
            const int* tk = (t == 0) ? nullptr : P.toks_cur;
            float* h_beam = P.hA;
            float* h_cur = (t == 0) ? P.h_tmp : h_beam;
            int nrt = N / 16;

            gather_k<<<N, 256, 0, stream>>>(N, Kc, mp, tk, h_beam, P.E, P.h_gF, P.xbufF);
            gemmF_k<1, true><<<dim3(3, nrt), 256, 0, stream>>>(
                Hdim, Hdim, Hdim, Hdim, P.h_gF, P.Ua, nullptr, P.hUa);
            attn2_k<<<N, 256, 0, stream>>>(N, Kc, P.hUa, P.srcWa, P.src, P.va, P.xbufF);
            gemmF_k<1, false><<<dim3(9, nrt), 256, 0, stream>>>(
                1536, 2304, 1536, 1536, P.xbufF, P.W_ih, P.b_ih, P.gx);
            gemmF_k<1, false><<<dim3(9, nrt), 256, 0, stream>>>(
                Hdim, 2304, Hdim, Hdim, P.h_gF, P.W_hh, P.b_hh, P.gh);
            gate_k<<<(N * Hdim + 255) / 256, 256, 0, stream>>>(N, P.gx, P.gh, P.h_gF, h_cur);
            if (t == 0)
                bcast_k<<<Bb, 256, 0, stream>>>(P.h_tmp, h_beam);
            gemmF_k<4, false><<<dim3(30, nrt), 256, 0, stream>>>(
                Hdim, Vv, Hdim, Hdim, h_cur, P.Wo, P.bo, P.logits);
            lse_k<<<N, 256, 0, stream>>>(N, P.logits, P.mx, P.lgs);
            topk5_k<<<Bb, 256, 0, stream>>>(t, P.logits, P.mx, P.lgs, P.scores,
                                            P.ended, P.lengths, P.toks_cur, P.maps_cur,
                                            P.toks_all, P.maps_all);
        }
        back_k<<<1, 64, 0, stream>>>(P.scores, P.toks_all, P.maps_all, P.outTok);
    }
}

// Round 10
// 49447.055 us; speedup vs baseline: 1.1468x; 1.1468x over previous
//
#include <hip/hip_runtime.h>
#include <cmath>

#define Hdim 768
#define Bb 32
#define Kb 5
#define Ss 64
#define Vv 30522
#define Tt 40
#define SEPTOK 102

typedef __attribute__((ext_vector_type(2))) float f32x2;
typedef __attribute__((ext_vector_type(4))) float f32x4;

// ---------------------------------------------------------------------------
// One-shot-weights GEMM: out[r,i] = chunked-f32-sum_p X[r*xrs+p] * W(p,i) (+bias)
// W(p,i) = PMAJ ? W[p*ldW + i] : W[i*ldW + p].
// Block: 512 thr as (ty=tid/32, tx=tid%32). Tile: (RPT*16 rows) x (CPT*32 cols).
// Thread micro-tile: RPT rows x CPT cols (static unrolled). K-chunk 32.
// Weights fetched once per (col-tile, row-tile); row-tiles = N/(RPT*16) kept at 1
// per step so each W matrix streams exactly once. P % 32 == 0; rows exact.
// Accumulation: per-chunk partial then __fadd_rn into running acc (proven class).
// ---------------------------------------------------------------------------
template<int RPT, int CPT, bool PMAJ>
__global__ __launch_bounds__(512) void gemmN_k(int P, int I, int xrs, int ldW,
    const float* __restrict__ X, const float* __restrict__ W,
    const float* __restrict__ bias, float* __restrict__ out, int ldO)
{
    constexpr int ROWS = RPT * 16;
    constexpr int COLS = CPT * 32;
    constexpr int XST  = ROWS + 4;          // even stride (8B-aligned f32x2 reads)
    constexpr int WST  = COLS + 4;
    __shared__ float xs[32][XST];           // [p][row]
    __shared__ float wt[32][WST];           // [p][col]
    const int tid = threadIdx.x;
    const int ty = tid >> 5, tx = tid & 31;
    const int row0 = blockIdx.y * ROWS;
    const int i0 = blockIdx.x * COLS;

    float acc[RPT][CPT];
#pragma unroll
    for (int j = 0; j < RPT; j++)
#pragma unroll
        for (int u = 0; u < CPT; u++) acc[j][u] = 0.f;

    for (int c0 = 0; c0 < P; c0 += 32) {
        __syncthreads();
        // ---- stage X chunk: ROWS x 32, coalesced reads, transposed to [p][r]
        for (int e = tid; e < ROWS * 32; e += 512) {
            int r = e >> 5, p = e & 31;
            xs[p][r] = X[(size_t)(row0 + r) * xrs + c0 + p];
        }
        // ---- stage W chunk: 32 x COLS
        if (PMAJ) {
            for (int v = tid; v < 32 * (COLS / 4); v += 512) {
                int p  = v / (COLS / 4);
                int i4 = (v % (COLS / 4)) * 4;
                f32x4 a;
                if (i0 + i4 + 3 < I) {
                    a = *(const f32x4*)&W[(size_t)(c0 + p) * ldW + i0 + i4];
                } else {
#pragma unroll
                    for (int u = 0; u < 4; u++) {
                        int g = i0 + i4 + u; if (g >= I) g = I - 1;
                        a[u] = W[(size_t)(c0 + p) * ldW + g];
                    }
                }
                *(f32x4*)&wt[p][i4] = a;
            }
        } else {
            for (int v = tid; v < COLS * 8; v += 512) {
                int c  = v >> 3;
                int p4 = (v & 7) * 4;
                int gi = i0 + c; if (gi >= I) gi = I - 1;
                f32x4 a = *(const f32x4*)&W[(size_t)gi * ldW + c0 + p4];
                wt[p4 + 0][c] = a[0]; wt[p4 + 1][c] = a[1];
                wt[p4 + 2][c] = a[2]; wt[p4 + 3][c] = a[3];
            }
        }
        __syncthreads();
        // ---- compute chunk partial (FMA-bound micro-tile)
        float part[RPT][CPT];
#pragma unroll
        for (int j = 0; j < RPT; j++)
#pragma unroll
            for (int u = 0; u < CPT; u++) part[j][u] = 0.f;
#pragma unroll
        for (int p = 0; p < 32; p++) {
            float xr[RPT];
#pragma unroll
            for (int j = 0; j < RPT; j += 2) {
                f32x2 xv = *(const f32x2*)&xs[p][ty * RPT + j];
                xr[j] = xv.x; xr[j + 1] = xv.y;
            }
            float wv[CPT];
#pragma unroll
            for (int u = 0; u < CPT; u += 2) {
                f32x2 w2 = *(const f32x2*)&wt[p][tx * CPT + u];
                wv[u] = w2.x; wv[u + 1] = w2.y;
            }
#pragma unroll
            for (int j = 0; j < RPT; j++)
#pragma unroll
                for (int u = 0; u < CPT; u++)
                    part[j][u] = fmaf(xr[j], wv[u], part[j][u]);
        }
#pragma unroll
        for (int j = 0; j < RPT; j++)
#pragma unroll
            for (int u = 0; u < CPT; u++)
                acc[j][u] = __fadd_rn(acc[j][u], part[j][u]);
    }
    // ---- write out
#pragma unroll
    for (int j = 0; j < RPT; j++) {
        int gr = row0 + ty * RPT + j;
#pragma unroll
        for (int u = 0; u < CPT; u++) {
            int gi = i0 + tx * CPT + u;
            if (gi < I) {
                float v = acc[j][u];
                if (bias) v = __fadd_rn(v, bias[gi]);
                out[(size_t)gr * ldO + gi] = v;
            }
        }
    }
}

// gather parent hidden + token embedding (all f32)
__global__ __launch_bounds__(256) void gather_k(int N, int Kcur,
    const int* __restrict__ maps, const int* __restrict__ toks,
    const float* __restrict__ h_beam, const float* __restrict__ E,
    float* __restrict__ h_g, float* __restrict__ xbuf)
{
    int n = blockIdx.x;
    if (n >= N) return;
    int b = n / Kcur;
    int tok = toks ? toks[n] : SEPTOK;
    const float* er = E + (size_t)tok * Hdim;
    if (maps) {
        const float* hs = h_beam + (size_t)(b * Kb + maps[n]) * Hdim;
        for (int j = threadIdx.x; j < Hdim; j += 256) {
            h_g[(size_t)n * Hdim + j]  = hs[j];
            xbuf[(size_t)n * 1536 + j] = er[j];
        }
    } else {
        for (int j = threadIdx.x; j < Hdim; j += 256) {
            h_g[(size_t)n * Hdim + j]  = 0.f;
            xbuf[(size_t)n * 1536 + j] = er[j];
        }
    }
}

__global__ __launch_bounds__(256) void bcast_k(const float* __restrict__ h_tmp,
                                               float* __restrict__ h_beam)
{
    int b = blockIdx.x;
    for (int j = threadIdx.x; j < Hdim; j += 256) {
        float v = h_tmp[(size_t)b * Hdim + j];
        for (int k = 0; k < Kb; k++)
            h_beam[(size_t)(b * Kb + k) * Hdim + j] = v;
    }
}

__global__ __launch_bounds__(256) void attn2_k(int N, int Kcur,
    const float* __restrict__ hUa, const float* __restrict__ srcWa,
    const float* __restrict__ src, const float* __restrict__ va,
    float* __restrict__ xbuf)
{
    __shared__ float hu[Hdim];
    __shared__ float va_s[Hdim];
    __shared__ float e_s[Ss];
    __shared__ float a_s[Ss];
    int n = blockIdx.x, tid = threadIdx.x;
    if (n >= N) return;
    int b = n / Kcur;
    for (int j = tid; j < Hdim; j += 256) {
        hu[j]   = hUa[(size_t)n * Hdim + j];
        va_s[j] = va[j];
    }
    __syncthreads();
    int wv = tid >> 6, ln = tid & 63;
    for (int s = wv * 16; s < wv * 16 + 16; s++) {
        const float* sw = srcWa + (size_t)(b * Ss + s) * Hdim;
        double p = 0.0;
        for (int j = ln; j < Hdim; j += 64) {
            float tv = (float)tanh((double)__fadd_rn(sw[j], hu[j]));
            p = ::fma((double)tv, (double)va_s[j], p);
        }
        for (int off = 32; off; off >>= 1) p += __shfl_down(p, off, 64);
        if (ln == 0) e_s[s] = (float)p;
    }
    __syncthreads();
    if (tid < 64) {
        float v = e_s[tid], m = v;
        for (int off = 32; off; off >>= 1) m = fmaxf(m, __shfl_xor(m, off, 64));
        float p = (float)exp((double)__fsub_rn(v, m));
        double sum = (double)p;
        for (int off = 32; off; off >>= 1) sum += __shfl_xor(sum, off, 64);
        a_s[tid] = __fdiv_rn(p, (float)sum);
    }
    __syncthreads();
    for (int j = tid; j < Hdim; j += 256) {
        double acc = 0.0;
        for (int s = 0; s < Ss; s++)
            acc = ::fma((double)a_s[s], (double)src[(size_t)(b * Ss + s) * Hdim + j], acc);
        xbuf[(size_t)n * 1536 + 768 + j] = (float)acc;
    }
}

__global__ __launch_bounds__(256) void gate_k(int N,
    const float* __restrict__ gx, const float* __restrict__ gh,
    const float* __restrict__ h_g, float* __restrict__ h_out)
{
    int idx = blockIdx.x * 256 + threadIdx.x;
    if (idx >= N * Hdim) return;
    int n = idx / Hdim, i = idx - n * Hdim;
    const float* gxr = gx + (size_t)n * 2304;
    const float* ghr = gh + (size_t)n * 2304;
    float xr = gxr[i], xz = gxr[768 + i], xn = gxr[1536 + i];
    float hr = ghr[i], hz = ghr[768 + i], hn = ghr[1536 + i];
    float r  = (float)(1.0 / (1.0 + exp(-(double)__fadd_rn(xr, hr))));
    float z  = (float)(1.0 / (1.0 + exp(-(double)__fadd_rn(xz, hz))));
    float nn = (float)tanh((double)__fadd_rn(xn, __fmul_rn(r, hn)));
    float hv = h_g[(size_t)n * Hdim + i];
    float h2 = __fadd_rn(__fmul_rn(__fsub_rn(1.f, z), nn), __fmul_rn(z, hv));
    h_out[(size_t)n * Hdim + i] = h2;
}

__global__ __launch_bounds__(256) void lse_k(int N,
    const float* __restrict__ logits, float* __restrict__ mx, float* __restrict__ lgs)
{
    __shared__ float  redf[256];
    __shared__ double redd[256];
    int n = blockIdx.x, tid = threadIdx.x;
    const float* lg = logits + (size_t)n * Vv;
    float m = -INFINITY;
    for (int v = tid; v < Vv; v += 256) m = fmaxf(m, lg[v]);
    redf[tid] = m; __syncthreads();
    for (int off = 128; off; off >>= 1) {
        if (tid < off) redf[tid] = fmaxf(redf[tid], redf[tid + off]);
        __syncthreads();
    }
    m = redf[0];
    double s = 0.0;
    for (int v = tid; v < Vv; v += 256) {
        float ex = (float)exp((double)__fsub_rn(lg[v], m));
        s += (double)ex;
    }
    redd[tid] = s; __syncthreads();
    for (int off = 128; off; off >>= 1) {
        if (tid < off) redd[tid] += redd[tid + off];
        __syncthreads();
    }
    if (tid == 0) {
        mx[n] = m;
        float sf = (float)redd[0];
        lgs[n] = (float)log((double)sf);
    }
}

// ------------------------- top-k helpers -----------------------------------
__device__ __forceinline__ bool betterf(float va, int ja, float vb, int jb) {
    return (va > vb) || (va == vb && ja < jb);
}
__device__ __forceinline__ void ins5(float* tv, int* tj, float v, int j) {
    if (!betterf(v, j, tv[4], tj[4])) return;
    tv[4] = v; tj[4] = j;
#pragma unroll
    for (int q = 4; q > 0; q--) {
        if (betterf(tv[q], tj[q], tv[q - 1], tj[q - 1])) {
            float t = tv[q]; tv[q] = tv[q - 1]; tv[q - 1] = t;
            int  ti = tj[q]; tj[q] = tj[q - 1]; tj[q - 1] = ti;
        }
    }
}

__global__ __launch_bounds__(256) void topk5_k(int t,
    const float* __restrict__ logits, const float* __restrict__ mx, const float* __restrict__ lgs,
    float* scores, float* ended, float* lengths,
    int* toks_cur, int* maps_cur, int* toks_all, int* maps_all)
{
    __shared__ float sc_s[Kb], den_s[Kb], end_s[Kb], len_s[Kb], mx_s[Kb], lg_s[Kb];
    __shared__ float mv[256 * 5];
    __shared__ int   mj[256 * 5];
    __shared__ float rv[256];
    __shared__ int   rj[256];
    __shared__ int   selj[Kb];
    int b = blockIdx.x, tid = threadIdx.x;
    int Kcur = (t == 0) ? 1 : Kb;
    if (tid < Kb) {
        if (t == 0) {
            sc_s[tid] = 0.f; end_s[tid] = 0.f; len_s[tid] = 0.f; den_s[tid] = 1.f;
            mx_s[tid] = mx[b]; lg_s[tid] = lgs[b];
        } else {
            float e0 = ended[b * Kb + tid];
            float ln = __fadd_rn(lengths[b * Kb + tid], (e0 == 0.f) ? 1.f : 0.f);
            sc_s[tid]  = scores[b * Kb + tid];
            end_s[tid] = e0;
            len_s[tid] = ln;
            den_s[tid] = (tid < Kb - 1) ? (float)pow((double)ln, (double)0.7f) : 1.f;
            mx_s[tid]  = mx[b * Kb + tid];
            lg_s[tid]  = lgs[b * Kb + tid];
        }
    }
    __syncthreads();
    const float* lbase = logits + (size_t)b * Kcur * Vv;
    float tv[5]; int tj[5];
#pragma unroll
    for (int q = 0; q < 5; q++) { tv[q] = -INFINITY; tj[q] = 0x7fffffff; }
    for (int k = 0; k < Kcur; k++) {
        if (end_s[k] == 0.f) {
            float m = mx_s[k], l = lg_s[k], sck = sc_s[k], den = den_s[k];
            const float* lg = lbase + (size_t)k * Vv;
            for (int v = tid; v < Vv; v += 256) {
                float lp  = __fsub_rn(__fsub_rn(lg[v], m), l);
                float val = __fdiv_rn(__fadd_rn(lp, sck), den);
                ins5(tv, tj, val, k * Vv + v);
            }
        } else if (tid == 0) {
            float val = __fdiv_rn(sc_s[k], den_s[k]);
            ins5(tv, tj, val, k * Vv + SEPTOK);
        }
    }
#pragma unroll
    for (int q = 0; q < 5; q++) { mv[tid * 5 + q] = tv[q]; mj[tid * 5 + q] = tj[q]; }
    __syncthreads();
    for (int pass = 0; pass < Kb; pass++) {
        float bv = -INFINITY; int bj = 0x7fffffff;
#pragma unroll
        for (int q = 0; q < 5; q++) {
            float v = mv[tid * 5 + q]; int j = mj[tid * 5 + q];
            if (betterf(v, j, bv, bj)) { bv = v; bj = j; }
        }
        rv[tid] = bv; rj[tid] = bj;
        __syncthreads();
        for (int off = 128; off; off >>= 1) {
            if (tid < off) {
                float ov = rv[tid + off]; int oj = rj[tid + off];
                if (betterf(ov, oj, rv[tid], rj[tid])) { rv[tid] = ov; rj[tid] = oj; }
            }
            __syncthreads();
        }
        if (tid == 0) selj[pass] = rj[0];
        __syncthreads();
#pragma unroll
        for (int q = 0; q < 5; q++)
            if (mj[tid * 5 + q] == selj[pass]) { mv[tid * 5 + q] = -INFINITY; mj[tid * 5 + q] = 0x7fffffff; }
        __syncthreads();
    }
    if (tid == 0) {
        for (int q = 0; q < Kb; q++) {
            int jj = selj[q];
            int pk = jj / Vv, vv = jj - pk * Vv;
            float lp;
            if (end_s[pk] == 0.f)
                lp = __fsub_rn(__fsub_rn(lbase[(size_t)pk * Vv + vv], mx_s[pk]), lg_s[pk]);
            else
                lp = (vv == SEPTOK) ? 0.f : -1e9f;
            float cand = __fadd_rn(lp, sc_s[pk]);
            scores[b * Kb + q]   = cand;
            toks_cur[b * Kb + q] = vv;
            maps_cur[b * Kb + q] = (t == 0) ? 0 : pk;
            if (t == 0) {
                ended[b * Kb + q]   = 0.f;
                lengths[b * Kb + q] = 0.f;
            } else {
                ended[b * Kb + q]   = (vv == SEPTOK) ? 1.f : end_s[q];
                lengths[b * Kb + q] = len_s[q];
            }
            toks_all[(size_t)t * Bb * Kb + b * Kb + q] = vv;
            maps_all[(size_t)t * Bb * Kb + b * Kb + q] = (t == 0) ? 0 : pk;
        }
    }
}

__global__ void back_k(const float* __restrict__ scores,
                       const int* __restrict__ toks_all, const int* __restrict__ maps_all,
                       int* __restrict__ out)
{
    int b = threadIdx.x;
    if (b >= Bb) return;
    int best = 0; float bvv = scores[b * Kb];
    for (int k = 1; k < Kb; k++) {
        float v = scores[b * Kb + k];
        if (v > bvv) { bvv = v; best = k; }
    }
    int cur = best;
    for (int t = Tt - 1; t >= 0; t--) {
        out[b * Tt + t] = toks_all[t * Bb * Kb + b * Kb + cur];
        cur = maps_all[t * Bb * Kb + b * Kb + cur];
    }
}

// ---------------------------------------------------------------------------
extern "C" void kernel_launch(void* const* d_in, const int* in_sizes, int n_in,
                              void* d_out, int out_size, void* d_ws, size_t ws_size,
                              hipStream_t stream)
{
    const float* src  = (const float*)d_in[0];
    const float* E    = (const float*)d_in[1];
    const float* Wa   = (const float*)d_in[2];
    const float* Ua   = (const float*)d_in[3];
    const float* va   = (const float*)d_in[4];
    const float* W_ih = (const float*)d_in[5];
    const float* W_hh = (const float*)d_in[6];
    const float* b_ih = (const float*)d_in[7];
    const float* b_hh = (const float*)d_in[8];
    const float* Wo   = (const float*)d_in[9];
    const float* bo   = (const float*)d_in[10];
    int* out = (int*)d_out;

    char* w = (char*)d_ws;
    size_t used = 0;
    auto alloc = [&](size_t bytes) -> char* {
        char* p = w + used;
        used += (bytes + 255) & ~(size_t)255;
        return p;
    };
    float*  srcWa   = (float*) alloc((size_t)Bb * Ss * Hdim * 4);
    float*  h_beam  = (float*) alloc((size_t)Bb * Kb * Hdim * 4);
    float*  h_tmp   = (float*) alloc((size_t)Bb * Hdim * 4);
    float*  h_g     = (float*) alloc((size_t)Bb * Kb * Hdim * 4);
    float*  hUa     = (float*) alloc((size_t)Bb * Kb * Hdim * 4);
    float*  xbuf    = (float*) alloc((size_t)Bb * Kb * 1536 * 4);
    float*  gx      = (float*) alloc((size_t)Bb * Kb * 2304 * 4);
    float*  gh      = (float*) alloc((size_t)Bb * Kb * 2304 * 4);
    float*  logits  = (float*) alloc((size_t)Bb * Kb * Vv * 4);
    float*  mx      = (float*) alloc(Bb * Kb * 4);
    float*  lgs     = (float*) alloc(Bb * Kb * 4);
    float*  scores  = (float*) alloc(Bb * Kb * 4);
    float*  ended   = (float*) alloc(Bb * Kb * 4);
    float*  lengths = (float*) alloc(Bb * Kb * 4);
    int* toks_cur = (int*)alloc(Bb * Kb * 4);
    int* maps_cur = (int*)alloc(Bb * Kb * 4);
    int* toks_all = (int*)alloc((size_t)Tt * Bb * Kb * 4);
    int* maps_all = (int*)alloc((size_t)Tt * Bb * Kb * 4);

    // srcWa = src @ Wa : N=2048 rows -> RPT=8 (128-row tiles, grid.y=16)
    gemmN_k<8, 2, true><<<dim3(12, 16), 512, 0, stream>>>(
        Hdim, Hdim, Hdim, Hdim, src, Wa, nullptr, srcWa, Hdim);

    for (int t = 0; t < Tt; t++) {
        int N  = (t == 0) ? Bb : Bb * Kb;
        int Kc = (t == 0) ? 1 : Kb;
        const int* mp = (t == 0) ? nullptr : maps_cur;
        const int* tk = (t == 0) ? nullptr : toks_cur;
        float* h_cur = (t == 0) ? h_tmp : h_beam;

        gather_k<<<N, 256, 0, stream>>>(N, Kc, mp, tk, h_beam, E, h_g, xbuf);
        if (t == 0) {
            gemmN_k<2, 2, true><<<dim3(12, 1), 512, 0, stream>>>(
                Hdim, Hdim, Hdim, Hdim, h_g, Ua, nullptr, hUa, Hdim);
        } else {
            gemmN_k<10, 2, true><<<dim3(12, 1), 512, 0, stream>>>(
                Hdim, Hdim, Hdim, Hdim, h_g, Ua, nullptr, hUa, Hdim);
        }
        attn2_k<<<N, 256, 0, stream>>>(N, Kc, hUa, srcWa, src, va, xbuf);
        if (t == 0) {
            gemmN_k<2, 2, false><<<dim3(36, 1), 512, 0, stream>>>(
                1536, 2304, 1536, 1536, xbuf, W_ih, b_ih, gx, 2304);
            gemmN_k<2, 2, false><<<dim3(36, 1), 512, 0, stream>>>(
                Hdim, 2304, Hdim, Hdim, h_g, W_hh, b_hh, gh, 2304);
        } else {
            gemmN_k<10, 2, false><<<dim3(36, 1), 512, 0, stream>>>(
                1536, 2304, 1536, 1536, xbuf, W_ih, b_ih, gx, 2304);
            gemmN_k<10, 2, false><<<dim3(36, 1), 512, 0, stream>>>(
                Hdim, 2304, Hdim, Hdim, h_g, W_hh, b_hh, gh, 2304);
        }
        gate_k<<<(N * Hdim + 255) / 256, 256, 0, stream>>>(N, gx, gh, h_g, h_cur);
        if (t == 0)
            bcast_k<<<Bb, 256, 0, stream>>>(h_tmp, h_beam);
        // logits = h2 @ Wo^T + bo : 239 col-tiles of 128
        if (t == 0) {
            gemmN_k<2, 4, false><<<dim3(239, 1), 512, 0, stream>>>(
                Hdim, Vv, Hdim, Hdim, h_cur, Wo, bo, logits, Vv);
        } else {
            gemmN_k<10, 4, false><<<dim3(239, 1), 512, 0, stream>>>(
                Hdim, Vv, Hdim, Hdim, h_cur, Wo, bo, logits, Vv);
        }
        lse_k<<<N, 256, 0, stream>>>(N, logits, mx, lgs);
        topk5_k<<<Bb, 256, 0, stream>>>(t, logits, mx, lgs, scores, ended, lengths,
                                        toks_cur, maps_cur, toks_all, maps_all);
    }
    back_k<<<1, 64, 0, stream>>>(scores, toks_all, maps_all, out);
}

// Round 11
// 46174.963 us; speedup vs baseline: 1.2281x; 1.0709x over previous
//
#include <hip/hip_runtime.h>
#include <hip/hip_cooperative_groups.h>
#include <cmath>

namespace cg = cooperative_groups;

#define Hdim 768
#define Bb 32
#define Kb 5
#define Ss 64
#define Vv 30522
#define Tt 40
#define SEPTOK 102
#define NTLOG 477   // ceil(30522/64)

typedef __attribute__((ext_vector_type(2))) float f32x2;
typedef __attribute__((ext_vector_type(4))) float f32x4;

struct Params {
    const float *src, *E, *Wa, *Ua, *va, *W_ih, *W_hh, *b_ih, *b_hh, *Wo, *bo;
    float *srcWa, *hA, *hB, *h_tmp, *h_g, *hUa, *xbuf, *gxE, *gx, *gh, *logits;
    float *maxpart, *mx, *lgs, *scores, *ended, *lengths;
    int *toks_cur, *maps_cur, *toks_all, *maps_all, *outTok;
};

// ------------------------- shared top-k helpers ----------------------------
__device__ __forceinline__ bool betterf(float va, int ja, float vb, int jb) {
    return (va > vb) || (va == vb && ja < jb);
}
__device__ __forceinline__ void ins5(float* tv, int* tj, float v, int j) {
    if (!betterf(v, j, tv[4], tj[4])) return;
    tv[4] = v; tj[4] = j;
#pragma unroll
    for (int q = 4; q > 0; q--) {
        if (betterf(tv[q], tj[q], tv[q - 1], tj[q - 1])) {
            float t = tv[q]; tv[q] = tv[q - 1]; tv[q - 1] = t;
            int  ti = tj[q]; tj[q] = tj[q - 1]; tj[q - 1] = ti;
        }
    }
}

// ======================= COOPERATIVE 4-SYNC PATH ===========================
union SMem {
    struct { float xs[32][162]; float wt[32][66]; } g;                     // ~29 KB
    struct { float hu[Hdim]; float va[Hdim]; float e[Ss]; float a[Ss];
             float ctx[Hdim]; float gx[2304]; } at;                        // ~19 KB
    struct { float sc[Kb], den[Kb], end[Kb], len[Kb], mxs[Kb], lgv[Kb];
             float mv[512 * 5]; int mj[512 * 5];
             float rv[512]; int rj[512]; double rd[512]; int selj[Kb]; } tk; // ~29 KB
};

// 160x64 one-shot-weight GEMM tile, 512 thr, micro-tile 10x2, K-chunk 32.
// xsrc: 0 = gathered h_old (zeros at t==0), 1 = emb tokens, 2 = h_new (rowMul t0)
// W(p,i) = pmaj ? W[(c0+p)*ldW + i] : W[i*ldW + c0+p]
__device__ void gemm512(SMem& sm, const Params& P, int t, int N, int xsrc,
    int i0, int Pdim, const float* __restrict__ W, int ldW, bool pmaj,
    const float* __restrict__ bias, float* __restrict__ outp, int ldO,
    int Icap, float* __restrict__ maxpart, int tileIdx)
{
    const int tid = threadIdx.x;
    const int ty = tid >> 5, tx = tid & 31;
    const float* h_old = (t & 1) ? P.hB : P.hA;
    const float* h_new = (t & 1) ? P.hA : P.hB;

    float acc[10][2];
#pragma unroll
    for (int j = 0; j < 10; j++) { acc[j][0] = 0.f; acc[j][1] = 0.f; }

    for (int c0 = 0; c0 < Pdim; c0 += 32) {
        __syncthreads();
        // stage X: 160 rows x 32 p -> xs[p][r] (coalesced global reads)
        for (int e = tid; e < 160 * 32; e += 512) {
            int r = e >> 5, p = e & 31;
            int n = (r < N) ? r : (N - 1);
            float v = 0.f;
            if (xsrc == 0) {
                if (t != 0) {
                    int par = (n / Kb) * Kb + P.maps_cur[n];
                    v = h_old[(size_t)par * Hdim + c0 + p];
                }
            } else if (xsrc == 1) {
                int tok = (t == 0) ? SEPTOK : P.toks_cur[n];
                v = P.E[(size_t)tok * Hdim + c0 + p];
            } else {
                int rowMul = (t == 0) ? Kb : 1;
                v = h_new[((size_t)n * rowMul) * Hdim + c0 + p];
            }
            sm.g.xs[p][r] = v;
        }
        // stage W: 32 p x 64 c -> wt[p][c]
        if (pmaj) {
            int p = tid >> 4, i4 = (tid & 15) * 4;
            int gi = i0 + i4;
            f32x4 a;
            if (gi + 3 < Icap) {
                a = *(const f32x4*)&W[(size_t)(c0 + p) * ldW + gi];
            } else {
#pragma unroll
                for (int u = 0; u < 4; u++) {
                    int g = gi + u; if (g >= Icap) g = Icap - 1;
                    a[u] = W[(size_t)(c0 + p) * ldW + g];
                }
            }
            *(f32x4*)&sm.g.wt[p][i4] = a;
        } else {
            int c = tid >> 3, p4 = (tid & 7) * 4;
            int gi = i0 + c; if (gi >= Icap) gi = Icap - 1;
            f32x4 a = *(const f32x4*)&W[(size_t)gi * ldW + c0 + p4];
            sm.g.wt[p4 + 0][c] = a[0]; sm.g.wt[p4 + 1][c] = a[1];
            sm.g.wt[p4 + 2][c] = a[2]; sm.g.wt[p4 + 3][c] = a[3];
        }
        __syncthreads();
        // chunk partial (two-level accumulation, proven noise class)
        float part[10][2];
#pragma unroll
        for (int j = 0; j < 10; j++) { part[j][0] = 0.f; part[j][1] = 0.f; }
#pragma unroll
        for (int p = 0; p < 32; p++) {
            f32x2 w2 = *(const f32x2*)&sm.g.wt[p][tx * 2];
            float xr[10];
#pragma unroll
            for (int j = 0; j < 10; j += 2) {
                f32x2 xv = *(const f32x2*)&sm.g.xs[p][ty * 10 + j];
                xr[j] = xv.x; xr[j + 1] = xv.y;
            }
#pragma unroll
            for (int j = 0; j < 10; j++) {
                part[j][0] = fmaf(xr[j], w2.x, part[j][0]);
                part[j][1] = fmaf(xr[j], w2.y, part[j][1]);
            }
        }
#pragma unroll
        for (int j = 0; j < 10; j++) {
            acc[j][0] = __fadd_rn(acc[j][0], part[j][0]);
            acc[j][1] = __fadd_rn(acc[j][1], part[j][1]);
        }
    }
    // write + row-max partials
    float rmax[10];
#pragma unroll
    for (int j = 0; j < 10; j++) rmax[j] = -INFINITY;
#pragma unroll
    for (int j = 0; j < 10; j++) {
        int r = ty * 10 + j;
        if (r < N) {
#pragma unroll
            for (int u = 0; u < 2; u++) {
                int gi = i0 + tx * 2 + u;
                if (gi < Icap) {
                    float v = acc[j][u];
                    if (bias) v = __fadd_rn(v, bias[gi]);
                    outp[(size_t)r * ldO + gi] = v;
                    rmax[j] = fmaxf(rmax[j], v);
                }
            }
        }
    }
    if (maxpart) {
#pragma unroll
        for (int j = 0; j < 10; j++) {
#pragma unroll
            for (int off = 16; off; off >>= 1)
                rmax[j] = fmaxf(rmax[j], __shfl_xor(rmax[j], off, 32));
        }
        if (tx == 0) {
#pragma unroll
            for (int j = 0; j < 10; j++) {
                int r = ty * 10 + j;
                if (r < N) maxpart[(size_t)tileIdx * 160 + r] = rmax[j];
            }
        }
    }
}

__global__ __launch_bounds__(512) void step_k(Params P)
{
    cg::grid_group grid = cg::this_grid();
    __shared__ SMem sm;
    const int tid = threadIdx.x;
    const int gdim = gridDim.x;

    for (int t = 0; t < Tt; t++) {
        const int N = (t == 0) ? Bb : Bb * Kb;
        const int Kcur = (t == 0) ? 1 : Kb;
        float* h_new = (t & 1) ? P.hA : P.hB;
        const float* h_old = (t & 1) ? P.hB : P.hA;

        // ---- P1: hUa (12) | gh (36) | gxE (36) ----
        for (int task = blockIdx.x; task < 84; task += gdim) {
            if (task < 12)
                gemm512(sm, P, t, N, 0, task * 64, Hdim, P.Ua, Hdim, true,
                        nullptr, P.hUa, Hdim, Hdim, nullptr, 0);
            else if (task < 48)
                gemm512(sm, P, t, N, 0, (task - 12) * 64, Hdim, P.W_hh, Hdim, false,
                        P.b_hh, P.gh, 2304, 2304, nullptr, 0);
            else
                gemm512(sm, P, t, N, 1, (task - 48) * 64, Hdim, P.W_ih, 1536, false,
                        nullptr, P.gxE, 2304, 2304, nullptr, 0);
        }
        grid.sync();

        // ---- P2: per-row attn + gxC matvec + gate -> h2 ----
        for (int n = blockIdx.x; n < N; n += gdim) {
            int b = n / Kcur;
            for (int j = tid; j < Hdim; j += 512) {
                sm.at.hu[j] = P.hUa[(size_t)n * Hdim + j];
                sm.at.va[j] = P.va[j];
            }
            __syncthreads();
            {
                int wv = tid >> 6, ln = tid & 63;
                for (int s = wv * 8; s < wv * 8 + 8; s++) {
                    const float* sw = P.srcWa + (size_t)(b * Ss + s) * Hdim;
                    double p = 0.0;
                    for (int j = ln; j < Hdim; j += 64) {
                        float tv = (float)tanh((double)__fadd_rn(sw[j], sm.at.hu[j]));
                        p = ::fma((double)tv, (double)sm.at.va[j], p);
                    }
                    for (int off = 32; off; off >>= 1) p += __shfl_down(p, off, 64);
                    if (ln == 0) sm.at.e[s] = (float)p;
                }
            }
            __syncthreads();
            if (tid < 64) {
                float v = sm.at.e[tid], m = v;
                for (int off = 32; off; off >>= 1) m = fmaxf(m, __shfl_xor(m, off, 64));
                float p = (float)exp((double)__fsub_rn(v, m));
                double sum = (double)p;
                for (int off = 32; off; off >>= 1) sum += __shfl_xor(sum, off, 64);
                sm.at.a[tid] = __fdiv_rn(p, (float)sum);
            }
            __syncthreads();
            for (int j = tid; j < Hdim; j += 512) {
                double acc = 0.0;
                for (int s = 0; s < Ss; s++)
                    acc = ::fma((double)sm.at.a[s],
                                (double)P.src[(size_t)(b * Ss + s) * Hdim + j], acc);
                sm.at.ctx[j] = (float)acc;
            }
            __syncthreads();
            // gx = gxE + ctx@W_ih(right)^T + b_ih   (chunk-32 partials)
            for (int i = tid; i < 2304; i += 512) {
                const float* wr = P.W_ih + (size_t)i * 1536 + 768;
                float accv = 0.f, part = 0.f;
                for (int p = 0; p < 768; p += 4) {
                    f32x4 w4 = *(const f32x4*)&wr[p];
                    part = fmaf(sm.at.ctx[p + 0], w4[0], part);
                    part = fmaf(sm.at.ctx[p + 1], w4[1], part);
                    part = fmaf(sm.at.ctx[p + 2], w4[2], part);
                    part = fmaf(sm.at.ctx[p + 3], w4[3], part);
                    if ((p & 31) == 28) { accv = __fadd_rn(accv, part); part = 0.f; }
                }
                sm.at.gx[i] = __fadd_rn(__fadd_rn(P.gxE[(size_t)n * 2304 + i], accv),
                                        P.b_ih[i]);
            }
            __syncthreads();
            int par = 0;
            if (t != 0) par = (n / Kb) * Kb + P.maps_cur[n];
            for (int i = tid; i < Hdim; i += 512) {
                float xr = sm.at.gx[i], xz = sm.at.gx[768 + i], xn = sm.at.gx[1536 + i];
                const float* ghr = P.gh + (size_t)n * 2304;
                float hr = ghr[i], hz = ghr[768 + i], hn = ghr[1536 + i];
                float r  = (float)(1.0 / (1.0 + exp(-(double)__fadd_rn(xr, hr))));
                float z  = (float)(1.0 / (1.0 + exp(-(double)__fadd_rn(xz, hz))));
                float nn = (float)tanh((double)__fadd_rn(xn, __fmul_rn(r, hn)));
                float hv = (t == 0) ? 0.f : h_old[(size_t)par * Hdim + i];
                float h2 = __fadd_rn(__fmul_rn(__fsub_rn(1.f, z), nn), __fmul_rn(z, hv));
                if (t == 0) {
                    for (int k = 0; k < Kb; k++)
                        h_new[(size_t)(n * Kb + k) * Hdim + i] = h2;
                } else {
                    h_new[(size_t)n * Hdim + i] = h2;
                }
            }
            __syncthreads();
        }
        grid.sync();

        // ---- P4: logits tiles + row-max partials ----
        for (int task = blockIdx.x; task < NTLOG; task += gdim) {
            gemm512(sm, P, t, N, 2, task * 64, Hdim, P.Wo, Hdim, false,
                    P.bo, P.logits, Vv, Vv, P.maxpart, task);
        }
        grid.sync();

        // ---- P5: per-batch fused max-reduce + lse + top-5 ----
        for (int b = blockIdx.x; b < Bb; b += gdim) {
            if (tid < Kb) {
                if (t == 0) {
                    sm.tk.sc[tid] = 0.f; sm.tk.end[tid] = 0.f; sm.tk.len[tid] = 0.f;
                    sm.tk.den[tid] = 1.f;
                } else {
                    float e0 = P.ended[b * Kb + tid];
                    float ln = __fadd_rn(P.lengths[b * Kb + tid], (e0 == 0.f) ? 1.f : 0.f);
                    sm.tk.sc[tid]  = P.scores[b * Kb + tid];
                    sm.tk.end[tid] = e0;
                    sm.tk.len[tid] = ln;
                    sm.tk.den[tid] = (tid < Kb - 1) ? (float)pow((double)ln, (double)0.7f) : 1.f;
                }
            }
            __syncthreads();
            for (int k = 0; k < Kcur; k++) {
                bool active = (t == 0) || (sm.tk.end[k] == 0.f);   // block-uniform
                if (!active) {
                    if (tid == 0) { sm.tk.mxs[k] = 0.f; sm.tk.lgv[k] = 0.f; }
                    __syncthreads();
                    continue;
                }
                int n = b * Kcur + k;
                float m = -INFINITY;
                for (int tile = tid; tile < NTLOG; tile += 512)
                    m = fmaxf(m, P.maxpart[(size_t)tile * 160 + n]);
                sm.tk.rv[tid] = m; __syncthreads();
                for (int off = 256; off; off >>= 1) {
                    if (tid < off) sm.tk.rv[tid] = fmaxf(sm.tk.rv[tid], sm.tk.rv[tid + off]);
                    __syncthreads();
                }
                m = sm.tk.rv[0];
                const float* lg = P.logits + (size_t)n * Vv;
                double s = 0.0;
                for (int v = tid; v < Vv; v += 512) {
                    float ex = (float)exp((double)__fsub_rn(lg[v], m));
                    s += (double)ex;
                }
                __syncthreads();
                sm.tk.rd[tid] = s; __syncthreads();
                for (int off = 256; off; off >>= 1) {
                    if (tid < off) sm.tk.rd[tid] += sm.tk.rd[tid + off];
                    __syncthreads();
                }
                if (tid == 0) {
                    sm.tk.mxs[k] = m;
                    float sf = (float)sm.tk.rd[0];
                    sm.tk.lgv[k] = (float)log((double)sf);
                }
                __syncthreads();
            }
            // top-5 scan
            const float* lbase = P.logits + (size_t)b * Kcur * Vv;
            float tv[5]; int tj[5];
#pragma unroll
            for (int q = 0; q < 5; q++) { tv[q] = -INFINITY; tj[q] = 0x7fffffff; }
            for (int k = 0; k < Kcur; k++) {
                if (t == 0 || sm.tk.end[k] == 0.f) {
                    float m = sm.tk.mxs[k], l = sm.tk.lgv[k];
                    float sck = sm.tk.sc[k], den = sm.tk.den[k];
                    const float* lg = lbase + (size_t)k * Vv;
                    for (int v = tid; v < Vv; v += 512) {
                        float lp  = __fsub_rn(__fsub_rn(lg[v], m), l);
                        float val = __fdiv_rn(__fadd_rn(lp, sck), den);
                        ins5(tv, tj, val, k * Vv + v);
                    }
                } else if (tid == 0) {
                    float val = __fdiv_rn(sm.tk.sc[k], sm.tk.den[k]);
                    ins5(tv, tj, val, k * Vv + SEPTOK);
                }
            }
#pragma unroll
            for (int q = 0; q < 5; q++) { sm.tk.mv[tid * 5 + q] = tv[q]; sm.tk.mj[tid * 5 + q] = tj[q]; }
            __syncthreads();
            for (int pass = 0; pass < Kb; pass++) {
                float bv = -INFINITY; int bj = 0x7fffffff;
#pragma unroll
                for (int q = 0; q < 5; q++) {
                    float v = sm.tk.mv[tid * 5 + q]; int j = sm.tk.mj[tid * 5 + q];
                    if (betterf(v, j, bv, bj)) { bv = v; bj = j; }
                }
                sm.tk.rv[tid] = bv; sm.tk.rj[tid] = bj;
                __syncthreads();
                for (int off = 256; off; off >>= 1) {
                    if (tid < off) {
                        float ov = sm.tk.rv[tid + off]; int oj = sm.tk.rj[tid + off];
                        if (betterf(ov, oj, sm.tk.rv[tid], sm.tk.rj[tid])) {
                            sm.tk.rv[tid] = ov; sm.tk.rj[tid] = oj;
                        }
                    }
                    __syncthreads();
                }
                if (tid == 0) sm.tk.selj[pass] = sm.tk.rj[0];
                __syncthreads();
#pragma unroll
                for (int q = 0; q < 5; q++)
                    if (sm.tk.mj[tid * 5 + q] == sm.tk.selj[pass]) {
                        sm.tk.mv[tid * 5 + q] = -INFINITY; sm.tk.mj[tid * 5 + q] = 0x7fffffff;
                    }
                __syncthreads();
            }
            if (tid == 0) {
                for (int q = 0; q < Kb; q++) {
                    int jj = sm.tk.selj[q];
                    int pk = jj / Vv, vv = jj - pk * Vv;
                    float lp;
                    if (t == 0 || sm.tk.end[pk] == 0.f)
                        lp = __fsub_rn(__fsub_rn(lbase[(size_t)pk * Vv + vv], sm.tk.mxs[pk]),
                                       sm.tk.lgv[pk]);
                    else
                        lp = (vv == SEPTOK) ? 0.f : -1e9f;
                    float cand = __fadd_rn(lp, sm.tk.sc[pk]);
                    P.scores[b * Kb + q]   = cand;
                    P.toks_cur[b * Kb + q] = vv;
                    P.maps_cur[b * Kb + q] = (t == 0) ? 0 : pk;
                    if (t == 0) {
                        P.ended[b * Kb + q]   = 0.f;
                        P.lengths[b * Kb + q] = 0.f;
                    } else {
                        P.ended[b * Kb + q]   = (vv == SEPTOK) ? 1.f : sm.tk.end[q];
                        P.lengths[b * Kb + q] = sm.tk.len[q];
                    }
                    P.toks_all[(size_t)t * Bb * Kb + b * Kb + q] = vv;
                    P.maps_all[(size_t)t * Bb * Kb + b * Kb + q] = (t == 0) ? 0 : pk;
                }
            }
            __syncthreads();
        }
        grid.sync();
    }

    if (blockIdx.x == 0 && tid < Bb) {
        int b = tid;
        int best = 0; float bvv = P.scores[b * Kb];
        for (int k = 1; k < Kb; k++) {
            float v = P.scores[b * Kb + k];
            if (v > bvv) { bvv = v; best = k; }
        }
        int cur = best;
        for (int t = Tt - 1; t >= 0; t--) {
            P.outTok[b * Tt + t] = P.toks_all[t * Bb * Kb + b * Kb + cur];
            cur = P.maps_all[t * Bb * Kb + b * Kb + cur];
        }
    }
}

// ===================== FALLBACK PATH (round-10, proven) ====================
template<int RPT, int CPT, bool PMAJ>
__global__ __launch_bounds__(512) void gemmN_k(int P, int I, int xrs, int ldW,
    const float* __restrict__ X, const float* __restrict__ W,
    const float* __restrict__ bias, float* __restrict__ out, int ldO)
{
    constexpr int ROWS = RPT * 16;
    constexpr int COLS = CPT * 32;
    constexpr int XST  = ROWS + 4;
    constexpr int WST  = COLS + 4;
    __shared__ float xs[32][XST];
    __shared__ float wt[32][WST];
    const int tid = threadIdx.x;
    const int ty = tid >> 5, tx = tid & 31;
    const int row0 = blockIdx.y * ROWS;
    const int i0 = blockIdx.x * COLS;

    float acc[RPT][CPT];
#pragma unroll
    for (int j = 0; j < RPT; j++)
#pragma unroll
        for (int u = 0; u < CPT; u++) acc[j][u] = 0.f;

    for (int c0 = 0; c0 < P; c0 += 32) {
        __syncthreads();
        for (int e = tid; e < ROWS * 32; e += 512) {
            int r = e >> 5, p = e & 31;
            xs[p][r] = X[(size_t)(row0 + r) * xrs + c0 + p];
        }
        if (PMAJ) {
            for (int v = tid; v < 32 * (COLS / 4); v += 512) {
                int p  = v / (COLS / 4);
                int i4 = (v % (COLS / 4)) * 4;
                f32x4 a;
                if (i0 + i4 + 3 < I) {
                    a = *(const f32x4*)&W[(size_t)(c0 + p) * ldW + i0 + i4];
                } else {
#pragma unroll
                    for (int u = 0; u < 4; u++) {
                        int g = i0 + i4 + u; if (g >= I) g = I - 1;
                        a[u] = W[(size_t)(c0 + p) * ldW + g];
                    }
                }
                *(f32x4*)&wt[p][i4] = a;
            }
        } else {
            for (int v = tid; v < COLS * 8; v += 512) {
                int c  = v >> 3;
                int p4 = (v & 7) * 4;
                int gi = i0 + c; if (gi >= I) gi = I - 1;
                f32x4 a = *(const f32x4*)&W[(size_t)gi * ldW + c0 + p4];
                wt[p4 + 0][c] = a[0]; wt[p4 + 1][c] = a[1];
                wt[p4 + 2][c] = a[2]; wt[p4 + 3][c] = a[3];
            }
        }
        __syncthreads();
        float part[RPT][CPT];
#pragma unroll
        for (int j = 0; j < RPT; j++)
#pragma unroll
            for (int u = 0; u < CPT; u++) part[j][u] = 0.f;
#pragma unroll
        for (int p = 0; p < 32; p++) {
            float xr[RPT];
#pragma unroll
            for (int j = 0; j < RPT; j += 2) {
                f32x2 xv = *(const f32x2*)&xs[p][ty * RPT + j];
                xr[j] = xv.x; xr[j + 1] = xv.y;
            }
            float wv[CPT];
#pragma unroll
            for (int u = 0; u < CPT; u += 2) {
                f32x2 w2 = *(const f32x2*)&wt[p][tx * CPT + u];
                wv[u] = w2.x; wv[u + 1] = w2.y;
            }
#pragma unroll
            for (int j = 0; j < RPT; j++)
#pragma unroll
                for (int u = 0; u < CPT; u++)
                    part[j][u] = fmaf(xr[j], wv[u], part[j][u]);
        }
#pragma unroll
        for (int j = 0; j < RPT; j++)
#pragma unroll
            for (int u = 0; u < CPT; u++)
                acc[j][u] = __fadd_rn(acc[j][u], part[j][u]);
    }
#pragma unroll
    for (int j = 0; j < RPT; j++) {
        int gr = row0 + ty * RPT + j;
#pragma unroll
        for (int u = 0; u < CPT; u++) {
            int gi = i0 + tx * CPT + u;
            if (gi < I) {
                float v = acc[j][u];
                if (bias) v = __fadd_rn(v, bias[gi]);
                out[(size_t)gr * ldO + gi] = v;
            }
        }
    }
}

__global__ __launch_bounds__(256) void gather_k(int N, int Kcur,
    const int* __restrict__ maps, const int* __restrict__ toks,
    const float* __restrict__ h_beam, const float* __restrict__ E,
    float* __restrict__ h_g, float* __restrict__ xbuf)
{
    int n = blockIdx.x;
    if (n >= N) return;
    int b = n / Kcur;
    int tok = toks ? toks[n] : SEPTOK;
    const float* er = E + (size_t)tok * Hdim;
    if (maps) {
        const float* hs = h_beam + (size_t)(b * Kb + maps[n]) * Hdim;
        for (int j = threadIdx.x; j < Hdim; j += 256) {
            h_g[(size_t)n * Hdim + j]  = hs[j];
            xbuf[(size_t)n * 1536 + j] = er[j];
        }
    } else {
        for (int j = threadIdx.x; j < Hdim; j += 256) {
            h_g[(size_t)n * Hdim + j]  = 0.f;
            xbuf[(size_t)n * 1536 + j] = er[j];
        }
    }
}

__global__ __launch_bounds__(256) void bcast_k(const float* __restrict__ h_tmp,
                                               float* __restrict__ h_beam)
{
    int b = blockIdx.x;
    for (int j = threadIdx.x; j < Hdim; j += 256) {
        float v = h_tmp[(size_t)b * Hdim + j];
        for (int k = 0; k < Kb; k++)
            h_beam[(size_t)(b * Kb + k) * Hdim + j] = v;
    }
}

__global__ __launch_bounds__(256) void attn2_k(int N, int Kcur,
    const float* __restrict__ hUa, const float* __restrict__ srcWa,
    const float* __restrict__ src, const float* __restrict__ va,
    float* __restrict__ xbuf)
{
    __shared__ float hu[Hdim];
    __shared__ float va_s[Hdim];
    __shared__ float e_s[Ss];
    __shared__ float a_s[Ss];
    int n = blockIdx.x, tid = threadIdx.x;
    if (n >= N) return;
    int b = n / Kcur;
    for (int j = tid; j < Hdim; j += 256) {
        hu[j]   = hUa[(size_t)n * Hdim + j];
        va_s[j] = va[j];
    }
    __syncthreads();
    int wv = tid >> 6, ln = tid & 63;
    for (int s = wv * 16; s < wv * 16 + 16; s++) {
        const float* sw = srcWa + (size_t)(b * Ss + s) * Hdim;
        double p = 0.0;
        for (int j = ln; j < Hdim; j += 64) {
            float tv = (float)tanh((double)__fadd_rn(sw[j], hu[j]));
            p = ::fma((double)tv, (double)va_s[j], p);
        }
        for (int off = 32; off; off >>= 1) p += __shfl_down(p, off, 64);
        if (ln == 0) e_s[s] = (float)p;
    }
    __syncthreads();
    if (tid < 64) {
        float v = e_s[tid], m = v;
        for (int off = 32; off; off >>= 1) m = fmaxf(m, __shfl_xor(m, off, 64));
        float p = (float)exp((double)__fsub_rn(v, m));
        double sum = (double)p;
        for (int off = 32; off; off >>= 1) sum += __shfl_xor(sum, off, 64);
        a_s[tid] = __fdiv_rn(p, (float)sum);
    }
    __syncthreads();
    for (int j = tid; j < Hdim; j += 256) {
        double acc = 0.0;
        for (int s = 0; s < Ss; s++)
            acc = ::fma((double)a_s[s], (double)src[(size_t)(b * Ss + s) * Hdim + j], acc);
        xbuf[(size_t)n * 1536 + 768 + j] = (float)acc;
    }
}

__global__ __launch_bounds__(256) void gate_k(int N,
    const float* __restrict__ gx, const float* __restrict__ gh,
    const float* __restrict__ h_g, float* __restrict__ h_out)
{
    int idx = blockIdx.x * 256 + threadIdx.x;
    if (idx >= N * Hdim) return;
    int n = idx / Hdim, i = idx - n * Hdim;
    const float* gxr = gx + (size_t)n * 2304;
    const float* ghr = gh + (size_t)n * 2304;
    float xr = gxr[i], xz = gxr[768 + i], xn = gxr[1536 + i];
    float hr = ghr[i], hz = ghr[768 + i], hn = ghr[1536 + i];
    float r  = (float)(1.0 / (1.0 + exp(-(double)__fadd_rn(xr, hr))));
    float z  = (float)(1.0 / (1.0 + exp(-(double)__fadd_rn(xz, hz))));
    float nn = (float)tanh((double)__fadd_rn(xn, __fmul_rn(r, hn)));
    float hv = h_g[(size_t)n * Hdim + i];
    float h2 = __fadd_rn(__fmul_rn(__fsub_rn(1.f, z), nn), __fmul_rn(z, hv));
    h_out[(size_t)n * Hdim + i] = h2;
}

__global__ __launch_bounds__(256) void lse_k(int N,
    const float* __restrict__ logits, float* __restrict__ mx, float* __restrict__ lgs)
{
    __shared__ float  redf[256];
    __shared__ double redd[256];
    int n = blockIdx.x, tid = threadIdx.x;
    const float* lg = logits + (size_t)n * Vv;
    float m = -INFINITY;
    for (int v = tid; v < Vv; v += 256) m = fmaxf(m, lg[v]);
    redf[tid] = m; __syncthreads();
    for (int off = 128; off; off >>= 1) {
        if (tid < off) redf[tid] = fmaxf(redf[tid], redf[tid + off]);
        __syncthreads();
    }
    m = redf[0];
    double s = 0.0;
    for (int v = tid; v < Vv; v += 256) {
        float ex = (float)exp((double)__fsub_rn(lg[v], m));
        s += (double)ex;
    }
    redd[tid] = s; __syncthreads();
    for (int off = 128; off; off >>= 1) {
        if (tid < off) redd[tid] += redd[tid + off];
        __syncthreads();
    }
    if (tid == 0) {
        mx[n] = m;
        float sf = (float)redd[0];
        lgs[n] = (float)log((double)sf);
    }
}

__global__ __launch_bounds__(256) void topk5_k(int t,
    const float* __restrict__ logits, const float* __restrict__ mx, const float* __restrict__ lgs,
    float* scores, float* ended, float* lengths,
    int* toks_cur, int* maps_cur, int* toks_all, int* maps_all)
{
    __shared__ float sc_s[Kb], den_s[Kb], end_s[Kb], len_s[Kb], mx_s[Kb], lg_s[Kb];
    __shared__ float mv[256 * 5];
    __shared__ int   mj[256 * 5];
    __shared__ float rv[256];
    __shared__ int   rj[256];
    __shared__ int   selj[Kb];
    int b = blockIdx.x, tid = threadIdx.x;
    int Kcur = (t == 0) ? 1 : Kb;
    if (tid < Kb) {
        if (t == 0) {
            sc_s[tid] = 0.f; end_s[tid] = 0.f; len_s[tid] = 0.f; den_s[tid] = 1.f;
            mx_s[tid] = mx[b]; lg_s[tid] = lgs[b];
        } else {
            float e0 = ended[b * Kb + tid];
            float ln = __fadd_rn(lengths[b * Kb + tid], (e0 == 0.f) ? 1.f : 0.f);
            sc_s[tid]  = scores[b * Kb + tid];
            end_s[tid] = e0;
            len_s[tid] = ln;
            den_s[tid] = (tid < Kb - 1) ? (float)pow((double)ln, (double)0.7f) : 1.f;
            mx_s[tid]  = mx[b * Kb + tid];
            lg_s[tid]  = lgs[b * Kb + tid];
        }
    }
    __syncthreads();
    const float* lbase = logits + (size_t)b * Kcur * Vv;
    float tv[5]; int tj[5];
#pragma unroll
    for (int q = 0; q < 5; q++) { tv[q] = -INFINITY; tj[q] = 0x7fffffff; }
    for (int k = 0; k < Kcur; k++) {
        if (end_s[k] == 0.f) {
            float m = mx_s[k], l = lg_s[k], sck = sc_s[k], den = den_s[k];
            const float* lg = lbase + (size_t)k * Vv;
            for (int v = tid; v < Vv; v += 256) {
                float lp  = __fsub_rn(__fsub_rn(lg[v], m), l);
                float val = __fdiv_rn(__fadd_rn(lp, sck), den);
                ins5(tv, tj, val, k * Vv + v);
            }
        } else if (tid == 0) {
            float val = __fdiv_rn(sc_s[k], den_s[k]);
            ins5(tv, tj, val, k * Vv + SEPTOK);
        }
    }
#pragma unroll
    for (int q = 0; q < 5; q++) { mv[tid * 5 + q] = tv[q]; mj[tid * 5 + q] = tj[q]; }
    __syncthreads();
    for (int pass = 0; pass < Kb; pass++) {
        float bv = -INFINITY; int bj = 0x7fffffff;
#pragma unroll
        for (int q = 0; q < 5; q++) {
            float v = mv[tid * 5 + q]; int j = mj[tid * 5 + q];
            if (betterf(v, j, bv, bj)) { bv = v; bj = j; }
        }
        rv[tid] = bv; rj[tid] = bj;
        __syncthreads();
        for (int off = 128; off; off >>= 1) {
            if (tid < off) {
                float ov = rv[tid + off]; int oj = rj[tid + off];
                if (betterf(ov, oj, rv[tid], rj[tid])) { rv[tid] = ov; rj[tid] = oj; }
            }
            __syncthreads();
        }
        if (tid == 0) selj[pass] = rj[0];
        __syncthreads();
#pragma unroll
        for (int q = 0; q < 5; q++)
            if (mj[tid * 5 + q] == selj[pass]) { mv[tid * 5 + q] = -INFINITY; mj[tid * 5 + q] = 0x7fffffff; }
        __syncthreads();
    }
    if (tid == 0) {
        for (int q = 0; q < Kb; q++) {
            int jj = selj[q];
            int pk = jj / Vv, vv = jj - pk * Vv;
            float lp;
            if (end_s[pk] == 0.f)
                lp = __fsub_rn(__fsub_rn(lbase[(size_t)pk * Vv + vv], mx_s[pk]), lg_s[pk]);
            else
                lp = (vv == SEPTOK) ? 0.f : -1e9f;
            float cand = __fadd_rn(lp, sc_s[pk]);
            scores[b * Kb + q]   = cand;
            toks_cur[b * Kb + q] = vv;
            maps_cur[b * Kb + q] = (t == 0) ? 0 : pk;
            if (t == 0) {
                ended[b * Kb + q]   = 0.f;
                lengths[b * Kb + q] = 0.f;
            } else {
                ended[b * Kb + q]   = (vv == SEPTOK) ? 1.f : end_s[q];
                lengths[b * Kb + q] = len_s[q];
            }
            toks_all[(size_t)t * Bb * Kb + b * Kb + q] = vv;
            maps_all[(size_t)t * Bb * Kb + b * Kb + q] = (t == 0) ? 0 : pk;
        }
    }
}

__global__ void back_k(const float* __restrict__ scores,
                       const int* __restrict__ toks_all, const int* __restrict__ maps_all,
                       int* __restrict__ out)
{
    int b = threadIdx.x;
    if (b >= Bb) return;
    int best = 0; float bvv = scores[b * Kb];
    for (int k = 1; k < Kb; k++) {
        float v = scores[b * Kb + k];
        if (v > bvv) { bvv = v; best = k; }
    }
    int cur = best;
    for (int t = Tt - 1; t >= 0; t--) {
        out[b * Tt + t] = toks_all[t * Bb * Kb + b * Kb + cur];
        cur = maps_all[t * Bb * Kb + b * Kb + cur];
    }
}

// ---------------------------------------------------------------------------
extern "C" void kernel_launch(void* const* d_in, const int* in_sizes, int n_in,
                              void* d_out, int out_size, void* d_ws, size_t ws_size,
                              hipStream_t stream)
{
    Params P;
    P.src  = (const float*)d_in[0];
    P.E    = (const float*)d_in[1];
    P.Wa   = (const float*)d_in[2];
    P.Ua   = (const float*)d_in[3];
    P.va   = (const float*)d_in[4];
    P.W_ih = (const float*)d_in[5];
    P.W_hh = (const float*)d_in[6];
    P.b_ih = (const float*)d_in[7];
    P.b_hh = (const float*)d_in[8];
    P.Wo   = (const float*)d_in[9];
    P.bo   = (const float*)d_in[10];
    P.outTok = (int*)d_out;

    char* w = (char*)d_ws;
    size_t used = 0;
    auto alloc = [&](size_t bytes) -> char* {
        char* p = w + used;
        used += (bytes + 255) & ~(size_t)255;
        return p;
    };
    P.srcWa   = (float*)alloc((size_t)Bb * Ss * Hdim * 4);
    P.hA      = (float*)alloc((size_t)Bb * Kb * Hdim * 4);
    P.hB      = (float*)alloc((size_t)Bb * Kb * Hdim * 4);
    P.h_tmp   = (float*)alloc((size_t)Bb * Hdim * 4);
    P.h_g     = (float*)alloc((size_t)Bb * Kb * Hdim * 4);
    P.hUa     = (float*)alloc((size_t)Bb * Kb * Hdim * 4);
    P.xbuf    = (float*)alloc((size_t)Bb * Kb * 1536 * 4);
    P.gxE     = (float*)alloc((size_t)Bb * Kb * 2304 * 4);
    P.gx      = (float*)alloc((size_t)Bb * Kb * 2304 * 4);
    P.gh      = (float*)alloc((size_t)Bb * Kb * 2304 * 4);
    P.logits  = (float*)alloc((size_t)Bb * Kb * Vv * 4);
    P.maxpart = (float*)alloc((size_t)NTLOG * 160 * 4);
    P.mx      = (float*)alloc(Bb * Kb * 4);
    P.lgs     = (float*)alloc(Bb * Kb * 4);
    P.scores  = (float*)alloc(Bb * Kb * 4);
    P.ended   = (float*)alloc(Bb * Kb * 4);
    P.lengths = (float*)alloc(Bb * Kb * 4);
    P.toks_cur = (int*)alloc(Bb * Kb * 4);
    P.maps_cur = (int*)alloc(Bb * Kb * 4);
    P.toks_all = (int*)alloc((size_t)Tt * Bb * Kb * 4);
    P.maps_all = (int*)alloc((size_t)Tt * Bb * Kb * 4);

    // one-time srcWa = src @ Wa (both paths consume it)
    gemmN_k<8, 2, true><<<dim3(12, 16), 512, 0, stream>>>(
        Hdim, Hdim, Hdim, Hdim, P.src, P.Wa, nullptr, P.srcWa, Hdim);

    // cooperative grid from real occupancy
    int dev = 0;
    (void)hipGetDevice(&dev);
    int nCU = 256;
    (void)hipDeviceGetAttribute(&nCU, hipDeviceAttributeMultiprocessorCount, dev);
    int maxAct = 0;
    if (hipOccupancyMaxActiveBlocksPerMultiprocessor(&maxAct, step_k, 512, 0)
            != hipSuccess || maxAct < 1)
        maxAct = 1;
    long long gridLL = (long long)maxAct * (long long)nCU;
    if (gridLL > 256) gridLL = 256;
    if (gridLL < 1) gridLL = 1;
    dim3 grid((unsigned)gridLL);

    void* args[] = { (void*)&P };
    hipError_t err = hipLaunchCooperativeKernel((void*)step_k, grid, dim3(512),
                                                args, 0, stream);
    if (err != hipSuccess) {
        (void)hipGetLastError();  // clear sticky error; run proven r10 fallback
        for (int t = 0; t < Tt; t++) {
            int N  = (t == 0) ? Bb : Bb * Kb;
            int Kc = (t == 0) ? 1 : Kb;
            const int* mp = (t == 0) ? nullptr : P.maps_cur;
            const int* tk = (t == 0) ? nullptr : P.toks_cur;
            float* h_beam = P.hA;
            float* h_cur = (t == 0) ? P.h_tmp : h_beam;

            gather_k<<<N, 256, 0, stream>>>(N, Kc, mp, tk, h_beam, P.E, P.h_g, P.xbuf);
            if (t == 0) {
                gemmN_k<2, 2, true><<<dim3(12, 1), 512, 0, stream>>>(
                    Hdim, Hdim, Hdim, Hdim, P.h_g, P.Ua, nullptr, P.hUa, Hdim);
            } else {
                gemmN_k<10, 2, true><<<dim3(12, 1), 512, 0, stream>>>(
                    Hdim, Hdim, Hdim, Hdim, P.h_g, P.Ua, nullptr, P.hUa, Hdim);
            }
            attn2_k<<<N, 256, 0, stream>>>(N, Kc, P.hUa, P.srcWa, P.src, P.va, P.xbuf);
            if (t == 0) {
                gemmN_k<2, 2, false><<<dim3(36, 1), 512, 0, stream>>>(
                    1536, 2304, 1536, 1536, P.xbuf, P.W_ih, P.b_ih, P.gx, 2304);
                gemmN_k<2, 2, false><<<dim3(36, 1), 512, 0, stream>>>(
                    Hdim, 2304, Hdim, Hdim, P.h_g, P.W_hh, P.b_hh, P.gh, 2304);
            } else {
                gemmN_k<10, 2, false><<<dim3(36, 1), 512, 0, stream>>>(
                    1536, 2304, 1536, 1536, P.xbuf, P.W_ih, P.b_ih, P.gx, 2304);
                gemmN_k<10, 2, false><<<dim3(36, 1), 512, 0, stream>>>(
                    Hdim, 2304, Hdim, Hdim, P.h_g, P.W_hh, P.b_hh, P.gh, 2304);
            }
            gate_k<<<(N * Hdim + 255) / 256, 256, 0, stream>>>(N, P.gx, P.gh, P.h_g, h_cur);
            if (t == 0)
                bcast_k<<<Bb, 256, 0, stream>>>(P.h_tmp, h_beam);
            if (t == 0) {
                gemmN_k<2, 4, false><<<dim3(239, 1), 512, 0, stream>>>(
                    Hdim, Vv, Hdim, Hdim, h_cur, P.Wo, P.bo, P.logits, Vv);
            } else {
                gemmN_k<10, 4, false><<<dim3(239, 1), 512, 0, stream>>>(
                    Hdim, Vv, Hdim, Hdim, h_cur, P.Wo, P.bo, P.logits, Vv);
            }
            lse_k<<<N, 256, 0, stream>>>(N, P.logits, P.mx, P.lgs);
            topk5_k<<<Bb, 256, 0, stream>>>(t, P.logits, P.mx, P.lgs, P.scores,
                                            P.ended, P.lengths, P.toks_cur, P.maps_cur,
                                            P.toks_all, P.maps_all);
        }
        back_k<<<1, 64, 0, stream>>>(P.scores, P.toks_all, P.maps_all, P.outTok);
    }
}